// Round 10
// baseline (889.976 us; speedup 1.0000x reference)
//
#include <hip/hip_runtime.h>
#include <cstdint>

namespace {
constexpr int kN = 50000;          // nodes per encoder
constexpr int kE = 200000;         // directed edges per encoder (pre self-loop)
constexpr int kE2 = kE + kN;       // with self loops (per encoder)
constexpr int kG = 256;            // graphs per encoder
constexpr float kNegSlope = 0.2f;
}

using half8   = __attribute__((ext_vector_type(8))) _Float16;
using half2v  = __attribute__((ext_vector_type(2))) _Float16;
using floatx4 = __attribute__((ext_vector_type(4))) float;

__device__ __forceinline__ void gld_lds16(const void* g, void* l) {
  __builtin_amdgcn_global_load_lds(
      (const __attribute__((address_space(1))) unsigned int*)g,
      (__attribute__((address_space(3))) unsigned int*)l, 16, 0, 0);
}

// fast exp: e^x = 2^(x*log2(e)) via hardware v_exp_f32 (no libm call)
__device__ __forceinline__ float fexp(float x) {
  return __builtin_amdgcn_exp2f(x * 1.44269504088896f);
}

// ---------------- fp16 MFMA GEMM: C[M,N] = A[M,K] @ B[K,N] -----------
// R22: BM templated — per-layer best configs from R8/R9 A/B:
//   l2 (K=512,N=512): BM=256, 8 waves, 4-slot ring dist-3  (R8: 101.5us;
//       R9's BM=128 regressed to 110 — staging traffic 615 vs 410 MB)
//   l1/l3 (K=64 / N=128): BM=128, 4 waves, 3-slot ring dist-2 (R9 total
//       improved via these layers)
// Schedule (verified R8/R9): counted vmcnt (never 0 in loop), ONE
// barrier per tile, stage kt+DIST into slot (kt-1)%RING — freed by the
// barrier since every wave's MFMAs for tile kt-1 issued before it.
template <int OUTF16, int BM, int BN, int CT>
__global__ __launch_bounds__((BM == 256) ? 512 : 256, 2) void gemm_ring(
    const _Float16* __restrict__ A, const _Float16* __restrict__ B,
    void* __restrict__ Cv, int M, int N, int K) {
  constexpr int THREADS = (BM == 256) ? 512 : 256;
  constexpr int ASL = BM * 4;              // A slots/tile (16B each)
  constexpr int BSL = BN * 4;              // B slots/tile
  constexpr int SLOT = (ASL + BSL) * 16;
  constexpr int LPT = (ASL + BSL) / THREADS;
  constexpr int RING = (BM == 256) ? 4 : 3;
  constexpr int DIST = RING - 1;
  constexpr int WAITN = (DIST - 1) * LPT;  // 8 / 6 / 4
  constexpr int WAVES = THREADS / 64;
  constexpr int WN = (BM == 256) ? 4 : 2;
  constexpr int WM = WAVES / WN;           // 2
  constexpr int WTM = BM / WM;             // 128 or 64
  constexpr int WTN = BN / WN;             // 64 or 128/64
  constexpr int MI = WTM / 16;
  constexpr int NI = WTN / 16;
  __shared__ alignas(16) char smem[RING * SLOT];
  const int t = threadIdx.x;
  const int w = t >> 6, l = t & 63;
  const int x = blockIdx.x & 7, s = blockIdx.x >> 3;
  const int col = (CT == 1) ? 0 : (s & (CT - 1));
  const int rt = ((CT == 1) ? s : (s >> 1)) * 8 + x;
  const int bm = rt * BM;
  const int bn = col * BN;
  if (bm >= M) return;  // padded row-tiles: whole block exits (no barrier)
  const int wr = w / WN, wc = w % WN;
  const int quad = l >> 4, lrow = l & 15;

  floatx4 acc[MI][NI];
#pragma unroll
  for (int mi = 0; mi < MI; ++mi)
#pragma unroll
    for (int ni = 0; ni < NI; ++ni) acc[mi][ni] = (floatx4){0.f, 0.f, 0.f, 0.f};

  // stage tile kt's A-part / B-part into the given ring slot
  auto stageA = [&](int slot, int kt) {
    char* buf = smem + (size_t)slot * SLOT;
    int k0 = kt * 32;
    k0 = (k0 > K - 32) ? (K - 32) : k0;  // clamp: beyond-NT garbage stays in-bounds
#pragma unroll
    for (int i = 0; i < ASL / THREADS; ++i) {
      const int sl = i * THREADS + t;
      const int row = ((sl >> 6) << 4) + (sl & 15);
      const int q = (sl >> 4) & 3;
      int ga = bm + row;
      ga = (ga < M) ? ga : (M - 1);      // clamp: keep lanes active
      gld_lds16(A + (size_t)ga * K + k0 + q * 8, buf + sl * 16);
    }
  };
  auto stageB = [&](int slot, int kt) {
    char* buf = smem + (size_t)slot * SLOT + ASL * 16;
    int k0 = kt * 32;
    k0 = (k0 > K - 32) ? (K - 32) : k0;
#pragma unroll
    for (int i = 0; i < BSL / THREADS; ++i) {
      const int sl = i * THREADS + t;
      const int row = ((sl >> 6) << 4) + (sl & 15);
      const int q = (sl >> 4) & 3;
      gld_lds16(B + (size_t)(bn + row) * K + k0 + q * 8, buf + sl * 16);
    }
  };

  // prologue: tiles 0..DIST-1 in flight (DIST*LPT loads)
#pragma unroll
  for (int p = 0; p < DIST; ++p) {
    stageA(p, p);
    stageB(p, p);
  }

  const int NT = K >> 5;
  int cur = 0;
  for (int kt = 0; kt < NT; ++kt) {
    char* bufc = smem + (size_t)cur * SLOT;
    const int stg = (cur == 0) ? (RING - 1) : (cur - 1);
    // outstanding: DIST tiles (DIST*LPT). Wait for tile kt's LPT.
    if constexpr (WAITN == 8)
      asm volatile("s_waitcnt vmcnt(8)" ::: "memory");
    else if constexpr (WAITN == 6)
      asm volatile("s_waitcnt vmcnt(6)" ::: "memory");
    else
      asm volatile("s_waitcnt vmcnt(4)" ::: "memory");
    __builtin_amdgcn_s_barrier();  // slot[cur] ready AND slot[stg] consumed
    asm volatile("" ::: "memory");
    stageA(stg, kt + DIST);        // -> slot of tile kt-1, safe after barrier
    half8 fa[MI], fb[NI];
#pragma unroll
    for (int ni = 0; ni < NI; ++ni)
      fb[ni] = *(const half8*)(bufc + ASL * 16 + ((wc * NI + ni) << 10) + l * 16);
#pragma unroll
    for (int mi = 0; mi < MI / 2; ++mi)
      fa[mi] = *(const half8*)(bufc + ((wr * MI + mi) << 10) + l * 16);
    __builtin_amdgcn_s_setprio(1);
#pragma unroll
    for (int mi = 0; mi < MI / 2; ++mi)
#pragma unroll
      for (int ni = 0; ni < NI; ++ni)
        acc[mi][ni] = __builtin_amdgcn_mfma_f32_16x16x32_f16(
            fa[mi], fb[ni], acc[mi][ni], 0, 0, 0);
    __builtin_amdgcn_s_setprio(0);
    stageB(stg, kt + DIST);        // remaining loads of tile kt+DIST
#pragma unroll
    for (int mi = MI / 2; mi < MI; ++mi)
      fa[mi] = *(const half8*)(bufc + ((wr * MI + mi) << 10) + l * 16);
    __builtin_amdgcn_s_setprio(1);
#pragma unroll
    for (int mi = MI / 2; mi < MI; ++mi)
#pragma unroll
      for (int ni = 0; ni < NI; ++ni)
        acc[mi][ni] = __builtin_amdgcn_mfma_f32_16x16x32_f16(
            fa[mi], fb[ni], acc[mi][ni], 0, 0, 0);
    __builtin_amdgcn_s_setprio(0);
    cur = (cur == RING - 1) ? 0 : (cur + 1);
    // no end-of-tile barrier: distance-DIST ring tolerates the drift
  }
  asm volatile("s_waitcnt vmcnt(0)" ::: "memory");  // drain garbage prefetches
  // epilogue: C/D layout col=lane&15, row=quad*4+reg
  const int colbase = bn + wc * WTN + lrow;
#pragma unroll
  for (int mi = 0; mi < MI; ++mi) {
    const int rbase = bm + wr * WTM + mi * 16 + quad * 4;
#pragma unroll
    for (int r = 0; r < 4; ++r) {
      const int grow = rbase + r;
      if (grow < M) {
        if constexpr (OUTF16) {
          _Float16* C = (_Float16*)Cv;
#pragma unroll
          for (int ni = 0; ni < NI; ++ni)
            C[(size_t)grow * N + colbase + ni * 16] = (_Float16)acc[mi][ni][r];
        } else {
          float* C = (float*)Cv;
#pragma unroll
          for (int ni = 0; ni < NI; ++ni)
            C[(size_t)grow * N + colbase + ni * 16] = acc[mi][ni][r];
        }
      }
    }
  }
}

// ------- all three weight transposes + f16 casts (fallback path) ------
__global__ void wt_split_all(const float* __restrict__ W1, _Float16* Th1,
                             const float* __restrict__ W2, _Float16* Th2,
                             const float* __restrict__ W3, _Float16* Th3) {
  int idx = blockIdx.x * blockDim.x + threadIdx.x;
  const float* W;
  _Float16* Th;
  int K, N;
  if (idx < 64 * 512) {
    W = W1; Th = Th1; K = 64; N = 512;
  } else if (idx < 64 * 512 + 512 * 512) {
    idx -= 64 * 512;
    W = W2; Th = Th2; K = 512; N = 512;
  } else if (idx < 64 * 512 + 512 * 512 + 512 * 128) {
    idx -= 64 * 512 + 512 * 512;
    W = W3; Th = Th3; K = 512; N = 128;
  } else {
    return;
  }
  const int k = idx / N;
  const int n = idx - k * N;
  Th[n * K + k] = (_Float16)W[idx];
}

// --- combined prep: x casts + cnt=1 + total=0 + weight transposes -----
__global__ void prep_all(const float* __restrict__ x0, const float* __restrict__ x1,
                         _Float16* __restrict__ Xh, int* __restrict__ cnt,
                         int* __restrict__ total,
                         const float* __restrict__ W1, _Float16* Th1,
                         const float* __restrict__ W2, _Float16* Th2,
                         const float* __restrict__ W3, _Float16* Th3) {
  const int idx = blockIdx.x * blockDim.x + threadIdx.x;
  const int half = kN * 64;
  if (idx < half) {
    Xh[idx] = (_Float16)x0[idx];
  } else if (idx < 2 * half) {
    Xh[idx] = (_Float16)x1[idx - half];
  } else {
    int e = idx - 2 * half;
    const float* W;
    _Float16* Th;
    int K, N;
    if (e < 64 * 512) {
      W = W1; Th = Th1; K = 64; N = 512;
    } else if (e < 64 * 512 + 512 * 512) {
      e -= 64 * 512;
      W = W2; Th = Th2; K = 512; N = 512;
    } else if (e < 64 * 512 + 512 * 512 + 512 * 128) {
      e -= 64 * 512 + 512 * 512;
      W = W3; Th = Th3; K = 512; N = 128;
    } else {
      W = nullptr; Th = nullptr; K = N = 0;
    }
    if (W) {
      const int k = e / N;
      const int n = e - k * N;
      Th[n * K + k] = (_Float16)W[e];
    }
  }
  if (idx < 2 * kN) cnt[idx] = 1;  // the self loop
  if (idx == 0) *total = 0;
}
// ------- single-encoder prep (fallback path) --------------------------
__global__ void prep(const float* __restrict__ X, _Float16* __restrict__ Xh,
                     int* __restrict__ cnt, int* __restrict__ total, int nsplit,
                     int n) {
  const int idx = blockIdx.x * blockDim.x + threadIdx.x;
  if (idx < nsplit) Xh[idx] = (_Float16)X[idx];
  if (idx < n) cnt[idx] = 1;
  if (idx == 0) *total = 0;
}

// ---------------- CSR (by dst) build ----------------------------------
__global__ void count_edges2(const int* __restrict__ d0, const int* __restrict__ d1,
                             int* __restrict__ cnt) {
  const int i = blockIdx.x * blockDim.x + threadIdx.x;
  if (i < kE) atomicAdd(&cnt[d0[i]], 1);
  else if (i < 2 * kE) atomicAdd(&cnt[d1[i - kE] + kN], 1);
}
__global__ void fill_edges2(const int* __restrict__ s0, const int* __restrict__ d0,
                            const int* __restrict__ s1, const int* __restrict__ d1,
                            int* __restrict__ cursor, int* __restrict__ csr) {
  const int i = blockIdx.x * blockDim.x + threadIdx.x;
  if (i < kE) {
    const int p = atomicAdd(&cursor[d0[i]], 1);
    csr[p] = s0[i];
  } else if (i < 2 * kE) {
    const int j = i - kE;
    const int p = atomicAdd(&cursor[d1[j] + kN], 1);
    csr[p] = s1[j] + kN;
  }
}
__global__ void count_edges(const int* __restrict__ dst, int* __restrict__ cnt,
                            int ne) {
  const int i = blockIdx.x * blockDim.x + threadIdx.x;
  if (i < ne) atomicAdd(&cnt[dst[i]], 1);
}
__global__ void fill_edges(const int* __restrict__ src, const int* __restrict__ dst,
                           int* __restrict__ cursor, int* __restrict__ csr, int ne) {
  const int i = blockIdx.x * blockDim.x + threadIdx.x;
  if (i < ne) {
    const int p = atomicAdd(&cursor[dst[i]], 1);
    csr[p] = src[i];
  }
}
__global__ void alloc_ranges(const int* __restrict__ cnt, int* __restrict__ start,
                             int* __restrict__ cursor, int* __restrict__ total,
                             int* __restrict__ csr, int n) {
  const int i = blockIdx.x * blockDim.x + threadIdx.x;
  const int lane = threadIdx.x & 63;
  const int v = (i < n) ? cnt[i] : 0;
  int sc = v;
#pragma unroll
  for (int off = 1; off < 64; off <<= 1) {
    const int t = __shfl_up(sc, off);
    if (lane >= off) sc += t;
  }
  const int wtot = __shfl(sc, 63);
  int base = 0;
  if (lane == 63) base = atomicAdd(total, wtot);
  base = __shfl(base, 63);
  const int st = base + sc - v;
  if (i < n) {
    start[i] = st;
    cursor[i] = st + 1;
    csr[st] = i;  // self loop first
  }
}

// ---------------- GAT aggregate, layers 1-2 (f16 h) -------------------
// R22: FOUR nodes per wave (R19's 2-node interleave was the win — the
// serial chain is per-NODE; 4 nodes = 8 independent gathers in flight).
// Gathered rows stay in half8 regs; FMAs use inline (float) casts so the
// compiler emits v_fma_mix (no f32 fragment arrays -> no spill).
__global__ void gat_agg4(const _Float16* __restrict__ h,
                         const float* __restrict__ a_src,
                         const float* __restrict__ a_dst,
                         const int* __restrict__ start, const int* __restrict__ cnt,
                         const int* __restrict__ csr_src,
                         const float* __restrict__ bias,
                         _Float16* __restrict__ outH, int n_nodes) {
  constexpr int ND = 4;
  const int gtid = blockIdx.x * blockDim.x + threadIdx.x;
  const int wid = gtid >> 6;
  const int lane = threadIdx.x & 63;
  const int base = wid * ND;
  if (base >= n_nodes) return;
  const int ch = lane * 8;
  float as_r[8], ad_r[8];
#pragma unroll
  for (int j = 0; j < 8; ++j) {
    as_r[j] = a_src[ch + j];
    ad_r[j] = a_dst[ch + j];
  }
  int nd[ND], sA[ND], cA[ND];
#pragma unroll
  for (int p = 0; p < ND; ++p) {
    const int n = base + p;
    nd[p] = (n < n_nodes) ? n : (n_nodes - 1);
  }
#pragma unroll
  for (int p = 0; p < ND; ++p) {
    sA[p] = start[nd[p]];
    cA[p] = (base + p < n_nodes) ? cnt[nd[p]] : 0;
  }
  // self gathers (csr[s]==node): dst-dot + self edge
  half8 vsel[ND];
#pragma unroll
  for (int p = 0; p < ND; ++p)
    vsel[p] = *(const half8*)(h + (size_t)nd[p] * 512 + ch);
  float ts[ND], td[ND];
#pragma unroll
  for (int p = 0; p < ND; ++p) {
    ts[p] = 0.f;
    td[p] = 0.f;
#pragma unroll
    for (int j = 0; j < 8; ++j) {
      ts[p] = fmaf((float)vsel[p][j], as_r[j], ts[p]);
      td[p] = fmaf((float)vsel[p][j], ad_r[j], td[p]);
    }
  }
#pragma unroll
  for (int off = 1; off < 16; off <<= 1)
#pragma unroll
    for (int p = 0; p < ND; ++p) {
      ts[p] += __shfl_xor(ts[p], off);
      td[p] += __shfl_xor(td[p], off);
    }
  float adv[ND], den[ND], acc[ND][8];
#pragma unroll
  for (int p = 0; p < ND; ++p) {
    adv[p] = td[p];
    float e = ts[p] + adv[p];
    e = (e > 0.f) ? e : kNegSlope * e;
    const float w = fexp(e);
    den[p] = w;
#pragma unroll
    for (int j = 0; j < 8; ++j) acc[p][j] = w * (float)vsel[p][j];
  }
  int cm = cA[0];
#pragma unroll
  for (int p = 1; p < ND; ++p) cm = (cA[p] > cm) ? cA[p] : cm;
  int i = 1;
  for (; i + 2 <= cm; i += 2) {
    int g0[ND], g1[ND];
#pragma unroll
    for (int p = 0; p < ND; ++p) {
      const int j0 = (i < cA[p]) ? i : 0;
      const int j1 = (i + 1 < cA[p]) ? (i + 1) : 0;
      g0[p] = csr_src[sA[p] + j0];
      g1[p] = csr_src[sA[p] + j1];
    }
    half8 v0[ND], v1[ND];
#pragma unroll
    for (int p = 0; p < ND; ++p) {
      v0[p] = *(const half8*)(h + (size_t)g0[p] * 512 + ch);
      v1[p] = *(const half8*)(h + (size_t)g1[p] * 512 + ch);
    }
    float t0[ND], t1[ND];
#pragma unroll
    for (int p = 0; p < ND; ++p) {
      t0[p] = 0.f;
      t1[p] = 0.f;
#pragma unroll
      for (int j = 0; j < 8; ++j) {
        t0[p] = fmaf((float)v0[p][j], as_r[j], t0[p]);
        t1[p] = fmaf((float)v1[p][j], as_r[j], t1[p]);
      }
    }
#pragma unroll
    for (int off = 1; off < 16; off <<= 1)
#pragma unroll
      for (int p = 0; p < ND; ++p) {
        t0[p] += __shfl_xor(t0[p], off);
        t1[p] += __shfl_xor(t1[p], off);
      }
#pragma unroll
    for (int p = 0; p < ND; ++p) {
      float e0 = t0[p] + adv[p];
      float e1 = t1[p] + adv[p];
      e0 = (e0 > 0.f) ? e0 : kNegSlope * e0;
      e1 = (e1 > 0.f) ? e1 : kNegSlope * e1;
      const float w0 = (i < cA[p]) ? fexp(e0) : 0.f;
      const float w1 = (i + 1 < cA[p]) ? fexp(e1) : 0.f;
      den[p] += w0 + w1;
#pragma unroll
      for (int j = 0; j < 8; ++j) {
        acc[p][j] = fmaf(w0, (float)v0[p][j], acc[p][j]);
        acc[p][j] = fmaf(w1, (float)v1[p][j], acc[p][j]);
      }
    }
  }
  if (i < cm) {  // tail: at most one edge per node
    int g0[ND];
#pragma unroll
    for (int p = 0; p < ND; ++p) {
      const int j0 = (i < cA[p]) ? i : 0;
      g0[p] = csr_src[sA[p] + j0];
    }
    half8 v0[ND];
#pragma unroll
    for (int p = 0; p < ND; ++p)
      v0[p] = *(const half8*)(h + (size_t)g0[p] * 512 + ch);
    float t0[ND];
#pragma unroll
    for (int p = 0; p < ND; ++p) {
      t0[p] = 0.f;
#pragma unroll
      for (int j = 0; j < 8; ++j)
        t0[p] = fmaf((float)v0[p][j], as_r[j], t0[p]);
    }
#pragma unroll
    for (int off = 1; off < 16; off <<= 1)
#pragma unroll
      for (int p = 0; p < ND; ++p) t0[p] += __shfl_xor(t0[p], off);
#pragma unroll
    for (int p = 0; p < ND; ++p) {
      float e0 = t0[p] + adv[p];
      e0 = (e0 > 0.f) ? e0 : kNegSlope * e0;
      const float w0 = (i < cA[p]) ? fexp(e0) : 0.f;
      den[p] += w0;
#pragma unroll
      for (int j = 0; j < 8; ++j)
        acc[p][j] = fmaf(w0, (float)v0[p][j], acc[p][j]);
    }
  }
#pragma unroll
  for (int p = 0; p < ND; ++p) {
    if (base + p < n_nodes) {
      const float inv = 1.f / (den[p] + 1e-16f);
      half8 H;
#pragma unroll
      for (int j = 0; j < 8; ++j) {
        float v = acc[p][j] * inv + bias[ch + j];
        v = (v > 0.f) ? v : (fexp(v) - 1.f);  // elu via hw exp
        H[j] = (_Float16)v;
      }
      *(half8*)(outH + (size_t)nd[p] * 512 + ch) = H;
    }
  }
}

// ---------- GAT aggregate, layer 3 (H=1, f16 h, 4 nodes/wave) ---------
__global__ void gat_agg_l3(const _Float16* __restrict__ h,
                           const float* __restrict__ a_src,
                           const float* __restrict__ a_dst,
                           const int* __restrict__ start, const int* __restrict__ cnt,
                           const int* __restrict__ csr_src,
                           const float* __restrict__ bias,
                           float* __restrict__ out, int n_nodes) {
  constexpr int ND = 4;
  const int gtid = blockIdx.x * blockDim.x + threadIdx.x;
  const int wid = gtid >> 6;
  const int lane = threadIdx.x & 63;
  const int base = wid * ND;
  if (base >= n_nodes) return;
  const float2 asv = *(const float2*)(a_src + lane * 2);
  const float2 adv2 = *(const float2*)(a_dst + lane * 2);
  int nd[ND], sA[ND], cA[ND];
#pragma unroll
  for (int p = 0; p < ND; ++p) {
    const int n = base + p;
    nd[p] = (n < n_nodes) ? n : (n_nodes - 1);
  }
#pragma unroll
  for (int p = 0; p < ND; ++p) {
    sA[p] = start[nd[p]];
    cA[p] = (base + p < n_nodes) ? cnt[nd[p]] : 0;
  }
  half2v vsel[ND];
#pragma unroll
  for (int p = 0; p < ND; ++p)
    vsel[p] = *(const half2v*)(h + (size_t)nd[p] * 128 + lane * 2);
  float ts[ND], td[ND];
#pragma unroll
  for (int p = 0; p < ND; ++p) {
    ts[p] = fmaf((float)vsel[p][0], asv.x, (float)vsel[p][1] * asv.y);
    td[p] = fmaf((float)vsel[p][0], adv2.x, (float)vsel[p][1] * adv2.y);
  }
#pragma unroll
  for (int off = 1; off < 64; off <<= 1)
#pragma unroll
    for (int p = 0; p < ND; ++p) {
      ts[p] += __shfl_xor(ts[p], off);
      td[p] += __shfl_xor(td[p], off);
    }
  float adv[ND], den[ND], ax[ND], ay[ND];
#pragma unroll
  for (int p = 0; p < ND; ++p) {
    adv[p] = td[p];
    float e = ts[p] + adv[p];
    e = (e > 0.f) ? e : kNegSlope * e;
    const float w = fexp(e);
    den[p] = w;
    ax[p] = w * (float)vsel[p][0];
    ay[p] = w * (float)vsel[p][1];
  }
  int cm = cA[0];
#pragma unroll
  for (int p = 1; p < ND; ++p) cm = (cA[p] > cm) ? cA[p] : cm;
  int i = 1;
  for (; i + 2 <= cm; i += 2) {
    int g0[ND], g1[ND];
#pragma unroll
    for (int p = 0; p < ND; ++p) {
      const int j0 = (i < cA[p]) ? i : 0;
      const int j1 = (i + 1 < cA[p]) ? (i + 1) : 0;
      g0[p] = csr_src[sA[p] + j0];
      g1[p] = csr_src[sA[p] + j1];
    }
    half2v v0[ND], v1[ND];
#pragma unroll
    for (int p = 0; p < ND; ++p) {
      v0[p] = *(const half2v*)(h + (size_t)g0[p] * 128 + lane * 2);
      v1[p] = *(const half2v*)(h + (size_t)g1[p] * 128 + lane * 2);
    }
    float t0[ND], t1[ND];
#pragma unroll
    for (int p = 0; p < ND; ++p) {
      t0[p] = fmaf((float)v0[p][0], asv.x, (float)v0[p][1] * asv.y);
      t1[p] = fmaf((float)v1[p][0], asv.x, (float)v1[p][1] * asv.y);
    }
#pragma unroll
    for (int off = 1; off < 64; off <<= 1)
#pragma unroll
      for (int p = 0; p < ND; ++p) {
        t0[p] += __shfl_xor(t0[p], off);
        t1[p] += __shfl_xor(t1[p], off);
      }
#pragma unroll
    for (int p = 0; p < ND; ++p) {
      float e0 = t0[p] + adv[p];
      float e1 = t1[p] + adv[p];
      e0 = (e0 > 0.f) ? e0 : kNegSlope * e0;
      e1 = (e1 > 0.f) ? e1 : kNegSlope * e1;
      const float w0 = (i < cA[p]) ? fexp(e0) : 0.f;
      const float w1 = (i + 1 < cA[p]) ? fexp(e1) : 0.f;
      den[p] += w0 + w1;
      ax[p] = fmaf(w0, (float)v0[p][0], ax[p]);
      ay[p] = fmaf(w0, (float)v0[p][1], ay[p]);
      ax[p] = fmaf(w1, (float)v1[p][0], ax[p]);
      ay[p] = fmaf(w1, (float)v1[p][1], ay[p]);
    }
  }
  if (i < cm) {
    int g0[ND];
#pragma unroll
    for (int p = 0; p < ND; ++p) {
      const int j0 = (i < cA[p]) ? i : 0;
      g0[p] = csr_src[sA[p] + j0];
    }
    half2v v0[ND];
#pragma unroll
    for (int p = 0; p < ND; ++p)
      v0[p] = *(const half2v*)(h + (size_t)g0[p] * 128 + lane * 2);
    float t0[ND];
#pragma unroll
    for (int p = 0; p < ND; ++p)
      t0[p] = fmaf((float)v0[p][0], asv.x, (float)v0[p][1] * asv.y);
#pragma unroll
    for (int off = 1; off < 64; off <<= 1)
#pragma unroll
      for (int p = 0; p < ND; ++p) t0[p] += __shfl_xor(t0[p], off);
#pragma unroll
    for (int p = 0; p < ND; ++p) {
      float e0 = t0[p] + adv[p];
      e0 = (e0 > 0.f) ? e0 : kNegSlope * e0;
      const float w0 = (i < cA[p]) ? fexp(e0) : 0.f;
      den[p] += w0;
      ax[p] = fmaf(w0, (float)v0[p][0], ax[p]);
      ay[p] = fmaf(w0, (float)v0[p][1], ay[p]);
    }
  }
#pragma unroll
  for (int p = 0; p < ND; ++p) {
    if (base + p < n_nodes) {
      const float inv = 1.f / (den[p] + 1e-16f);
      *(float2*)(out + (size_t)nd[p] * 128 + lane * 2) =
          make_float2(ax[p] * inv + bias[lane * 2],
                      ay[p] * inv + bias[lane * 2 + 1]);
    }
  }
}

// ------- global max pool over sorted batch (both encoders, 1 launch) ---
__global__ void pool_max2(const float* __restrict__ x, const int* __restrict__ bt1,
                          const int* __restrict__ bt2, float* __restrict__ emb) {
  __shared__ int lohi[2];
  const int enc = blockIdx.x >> 8;
  const int g = blockIdx.x & 255;
  const int* batch = enc ? bt2 : bt1;
  const float* xx = x + (size_t)enc * kN * 128;
  if (threadIdx.x == 0) {
    int lo = 0, hi = kN;
    while (lo < hi) {
      const int mid = (lo + hi) >> 1;
      if (batch[mid] < g) lo = mid + 1; else hi = mid;
    }
    lohi[0] = lo;
    hi = kN;
    while (lo < hi) {
      const int mid = (lo + hi) >> 1;
      if (batch[mid] < g + 1) lo = mid + 1; else hi = mid;
    }
    lohi[1] = lo;
  }
  __syncthreads();
  const int lo = lohi[0], hi = lohi[1];
  const int c = threadIdx.x;  // 128 channels
  float m = -1e30f;
  for (int nid = lo; nid < hi; ++nid) m = fmaxf(m, xx[(size_t)nid * 128 + c]);
  emb[(size_t)blockIdx.x * 128 + c] = (lo < hi) ? m : 0.f;
}
// ------- single-encoder pool (fallback path) --------------------------
__global__ void pool_max(const float* __restrict__ x, const int* __restrict__ batch,
                         float* __restrict__ emb, int n_nodes) {
  __shared__ int lohi[2];
  const int g = blockIdx.x;
  if (threadIdx.x == 0) {
    int lo = 0, hi = n_nodes;
    while (lo < hi) {
      const int mid = (lo + hi) >> 1;
      if (batch[mid] < g) lo = mid + 1; else hi = mid;
    }
    lohi[0] = lo;
    hi = n_nodes;
    while (lo < hi) {
      const int mid = (lo + hi) >> 1;
      if (batch[mid] < g + 1) lo = mid + 1; else hi = mid;
    }
    lohi[1] = lo;
  }
  __syncthreads();
  const int lo = lohi[0], hi = lohi[1];
  const int c = threadIdx.x;  // 128 channels
  float m = -1e30f;
  for (int nid = lo; nid < hi; ++nid) m = fmaxf(m, x[(size_t)nid * 128 + c]);
  emb[g * 128 + c] = (lo < hi) ? m : 0.f;
}

// ---------------- final MLP head --------------------------------------
__global__ void mlp_head(const float* __restrict__ e1, const float* __restrict__ e2,
                         const float* __restrict__ mw1, const float* __restrict__ mb1,
                         const float* __restrict__ mw2, const float* __restrict__ mb2,
                         float* __restrict__ out) {
  __shared__ float z[256];
  __shared__ float red[128];
  const int g = blockIdx.x;
  const int j = threadIdx.x;  // 128
  z[j] = e1[g * 128 + j];
  z[j + 128] = e2[g * 128 + j];
  __syncthreads();
  float acc = mb1[j];
  for (int k = 0; k < 256; ++k) acc = fmaf(z[k], mw1[k * 128 + j], acc);
  acc = fmaxf(acc, 0.f) * mw2[j];
  red[j] = acc;
  __syncthreads();
  for (int s = 64; s > 0; s >>= 1) {
    if (j < s) red[j] += red[j + s];
    __syncthreads();
  }
  if (j == 0) out[g] = red[0] + mb2[0];
}

// ---------------- launcher --------------------------------------------
namespace {
struct Bufs {
  _Float16 *R1h, *R2h;
  float *R1f, *R2f, *asrc, *adst;
  int *cnt, *start, *cursor, *csr, *total;
  _Float16 *Wth1, *Wth2, *Wth3;
  float* emb;
  size_t need;
};

Bufs plan(void* d_ws, int M, int E) {
  Bufs b;
  char* w = (char*)d_ws;
  size_t off = 0;
  auto take = [&](size_t bytes) -> void* {
    void* p = w + off;
    off += (bytes + 255) & ~(size_t)255;
    return p;
  };
  b.R1h = (_Float16*)take((size_t)M * 512 * 2);  // f16 activations
  b.R1f = (float*)b.R1h;                         // layer-3 out alias [M,128]
  b.R2h = (_Float16*)take((size_t)M * 512 * 2);  // h f16 (l3 h f16 [M,128])
  b.R2f = (float*)b.R2h;
  b.asrc = (float*)take((size_t)M * 4 * 4);      // (kept for ws layout stability)
  b.adst = (float*)take((size_t)M * 4 * 4);
  b.cnt = (int*)take((size_t)M * 4);
  b.start = (int*)take((size_t)M * 4);
  b.cursor = (int*)take((size_t)M * 4);
  b.csr = (int*)take((size_t)E * 4);
  b.total = (int*)take(256);
  b.Wth1 = (_Float16*)take((size_t)64 * 512 * 2);
  b.Wth2 = (_Float16*)take((size_t)512 * 512 * 2);
  b.Wth3 = (_Float16*)take((size_t)512 * 128 * 2);
  b.emb = (float*)take((size_t)2 * kG * 128 * 4);
  b.need = off;
  return b;
}

void run_layers(const Bufs& b, void* const* d_in, int M, hipStream_t stream) {
  const float* as1 = (const float*)d_in[7];
  const float* ad1 = (const float*)d_in[8];
  const float* b1 = (const float*)d_in[9];
  const float* as2 = (const float*)d_in[11];
  const float* ad2 = (const float*)d_in[12];
  const float* b2 = (const float*)d_in[13];
  const float* as3 = (const float*)d_in[15];
  const float* ad3 = (const float*)d_in[16];
  const float* b3 = (const float*)d_in[17];
  const int aggBlocks = (((M + 3) / 4) * 64 + 255) / 256;  // 4 nodes/wave
  const int RT128 = (M + 127) / 128;
  const int SP128 = (RT128 + 7) / 8;      // 128-row tile groups (XCD map)
  const int RT256 = (M + 255) / 256;
  const int SP256 = (RT256 + 7) / 8;      // 256-row tile groups

  // layer 1: [M,64] @ [64,512], BM=128 (K=64: small tile wins — R9)
  gemm_ring<1, 128, 256, 2><<<SP128 * 16, 256, 0, stream>>>(b.R1h, b.Wth1, b.R2h,
                                                            M, 512, 64);
  gat_agg4<<<aggBlocks, 256, 0, stream>>>(b.R2h, as1, ad1, b.start, b.cnt,
                                          b.csr, b1, b.R1h, M);
  // layer 2: [M,512] @ [512,512], BM=256 (best measured config — R8)
  gemm_ring<1, 256, 256, 2><<<SP256 * 16, 512, 0, stream>>>(b.R1h, b.Wth2, b.R2h,
                                                            M, 512, 512);
  gat_agg4<<<aggBlocks, 256, 0, stream>>>(b.R2h, as2, ad2, b.start, b.cnt,
                                          b.csr, b2, b.R1h, M);
  // layer 3: [M,512] @ [512,128], BM=128, h -> f16
  gemm_ring<1, 128, 128, 1><<<SP128 * 8, 256, 0, stream>>>(b.R1h, b.Wth3, b.R2h,
                                                           M, 128, 512);
  gat_agg_l3<<<aggBlocks, 256, 0, stream>>>(b.R2h, as3, ad3, b.start, b.cnt,
                                            b.csr, b3, b.R1f, M);
}
}  // namespace

extern "C" void kernel_launch(void* const* d_in, const int* in_sizes, int n_in,
                              void* d_out, int out_size, void* d_ws, size_t ws_size,
                              hipStream_t stream) {
  (void)in_sizes; (void)n_in; (void)out_size;
  const float* W1 = (const float*)d_in[6];
  const float* W2 = (const float*)d_in[10];
  const float* W3 = (const float*)d_in[14];
  const float* mw1 = (const float*)d_in[18];
  const float* mb1 = (const float*)d_in[19];
  const float* mw2 = (const float*)d_in[20];
  const float* mb2 = (const float*)d_in[21];

  // Prefer combined (both encoders batched, M=2N) if it fits the workspace.
  Bufs bc = plan(d_ws, 2 * kN, 2 * kE2);
  const bool combined = bc.need <= ws_size;
  Bufs b = combined ? bc : plan(d_ws, kN, kE2);

  const int wtot = 64 * 512 + 512 * 512 + 512 * 128;
  if (combined) {
    const int M = 2 * kN;
    const int* ei0 = (const int*)d_in[1];
    const int* ei1 = (const int*)d_in[4];
    prep_all<<<(M * 64 + wtot + 255) / 256, 256, 0, stream>>>(
        (const float*)d_in[0], (const float*)d_in[3], b.R1h, b.cnt, b.total,
        W1, b.Wth1, W2, b.Wth2, W3, b.Wth3);
    count_edges2<<<(2 * kE + 255) / 256, 256, 0, stream>>>(ei0 + kE, ei1 + kE,
                                                           b.cnt);
    alloc_ranges<<<(M + 255) / 256, 256, 0, stream>>>(b.cnt, b.start, b.cursor,
                                                      b.total, b.csr, M);
    fill_edges2<<<(2 * kE + 255) / 256, 256, 0, stream>>>(ei0, ei0 + kE, ei1,
                                                          ei1 + kE, b.cursor, b.csr);
    run_layers(b, d_in, M, stream);
    pool_max2<<<2 * kG, 128, 0, stream>>>(b.R1f, (const int*)d_in[2],
                                          (const int*)d_in[5], b.emb);
  } else {
    wt_split_all<<<(wtot + 255) / 256, 256, 0, stream>>>(W1, b.Wth1, W2, b.Wth2,
                                                         W3, b.Wth3);
    for (int enc = 0; enc < 2; ++enc) {
      const float* x = (const float*)d_in[enc * 3 + 0];
      const int* ei = (const int*)d_in[enc * 3 + 1];
      const int* batch = (const int*)d_in[enc * 3 + 2];
      prep<<<(kN * 64 + 255) / 256, 256, 0, stream>>>(x, b.R1h, b.cnt, b.total,
                                                      kN * 64, kN);
      count_edges<<<(kE + 255) / 256, 256, 0, stream>>>(ei + kE, b.cnt, kE);
      alloc_ranges<<<(kN + 255) / 256, 256, 0, stream>>>(b.cnt, b.start, b.cursor,
                                                         b.total, b.csr, kN);
      fill_edges<<<(kE + 255) / 256, 256, 0, stream>>>(ei, ei + kE, b.cursor, b.csr,
                                                       kE);
      run_layers(b, d_in, kN, stream);
      pool_max<<<kG, 128, 0, stream>>>(b.R1f, batch, b.emb + (size_t)enc * kG * 128,
                                       kN);
    }
  }
  mlp_head<<<kG, 128, 0, stream>>>(b.emb, b.emb + (size_t)kG * 128, mw1, mb1, mw2,
                                   mb2, (float*)d_out);
}

// Round 11
// 633.410 us; speedup vs baseline: 1.4051x; 1.4051x over previous
//
#include <hip/hip_runtime.h>
#include <cstdint>

namespace {
constexpr int kN = 50000;          // nodes per encoder
constexpr int kE = 200000;         // directed edges per encoder (pre self-loop)
constexpr int kE2 = kE + kN;       // with self loops (per encoder)
constexpr int kG = 256;            // graphs per encoder
constexpr float kNegSlope = 0.2f;
}

using half8   = __attribute__((ext_vector_type(8))) _Float16;
using half2v  = __attribute__((ext_vector_type(2))) _Float16;
using floatx4 = __attribute__((ext_vector_type(4))) float;

__device__ __forceinline__ void gld_lds16(const void* g, void* l) {
  __builtin_amdgcn_global_load_lds(
      (const __attribute__((address_space(1))) unsigned int*)g,
      (__attribute__((address_space(3))) unsigned int*)l, 16, 0, 0);
}

// fast exp: e^x = 2^(x*log2(e)) via hardware v_exp_f32 (no libm call)
__device__ __forceinline__ float fexp(float x) {
  return __builtin_amdgcn_exp2f(x * 1.44269504088896f);
}

// ---------------- fp16 MFMA GEMM: C[M,N] = A[M,K] @ B[K,N] -----------
// R23 (= R22 GEMM, kept): BM templated — per-layer best configs:
//   l2 (K=512,N=512): BM=256, 8 waves, 4-slot ring dist-3  (R8: 101.5us)
//   l1/l3 (K=64 / N=128): BM=128, 4 waves, 3-slot ring dist-2 (R9 win)
// Schedule (verified R8/R9): counted vmcnt (never 0 in loop), ONE
// barrier per tile, stage kt+DIST into slot (kt-1)%RING — freed by the
// barrier since every wave's MFMAs for tile kt-1 issued before it.
template <int OUTF16, int BM, int BN, int CT>
__global__ __launch_bounds__((BM == 256) ? 512 : 256, 2) void gemm_ring(
    const _Float16* __restrict__ A, const _Float16* __restrict__ B,
    void* __restrict__ Cv, int M, int N, int K) {
  constexpr int THREADS = (BM == 256) ? 512 : 256;
  constexpr int ASL = BM * 4;              // A slots/tile (16B each)
  constexpr int BSL = BN * 4;              // B slots/tile
  constexpr int SLOT = (ASL + BSL) * 16;
  constexpr int LPT = (ASL + BSL) / THREADS;
  constexpr int RING = (BM == 256) ? 4 : 3;
  constexpr int DIST = RING - 1;
  constexpr int WAITN = (DIST - 1) * LPT;  // 8 / 6 / 4
  constexpr int WAVES = THREADS / 64;
  constexpr int WN = (BM == 256) ? 4 : 2;
  constexpr int WM = WAVES / WN;           // 2
  constexpr int WTM = BM / WM;             // 128 or 64
  constexpr int WTN = BN / WN;             // 64 or 128/64
  constexpr int MI = WTM / 16;
  constexpr int NI = WTN / 16;
  __shared__ alignas(16) char smem[RING * SLOT];
  const int t = threadIdx.x;
  const int w = t >> 6, l = t & 63;
  const int x = blockIdx.x & 7, s = blockIdx.x >> 3;
  const int col = (CT == 1) ? 0 : (s & (CT - 1));
  const int rt = ((CT == 1) ? s : (s >> 1)) * 8 + x;
  const int bm = rt * BM;
  const int bn = col * BN;
  if (bm >= M) return;  // padded row-tiles: whole block exits (no barrier)
  const int wr = w / WN, wc = w % WN;
  const int quad = l >> 4, lrow = l & 15;

  floatx4 acc[MI][NI];
#pragma unroll
  for (int mi = 0; mi < MI; ++mi)
#pragma unroll
    for (int ni = 0; ni < NI; ++ni) acc[mi][ni] = (floatx4){0.f, 0.f, 0.f, 0.f};

  // stage tile kt's A-part / B-part into the given ring slot
  auto stageA = [&](int slot, int kt) {
    char* buf = smem + (size_t)slot * SLOT;
    int k0 = kt * 32;
    k0 = (k0 > K - 32) ? (K - 32) : k0;  // clamp: beyond-NT garbage stays in-bounds
#pragma unroll
    for (int i = 0; i < ASL / THREADS; ++i) {
      const int sl = i * THREADS + t;
      const int row = ((sl >> 6) << 4) + (sl & 15);
      const int q = (sl >> 4) & 3;
      int ga = bm + row;
      ga = (ga < M) ? ga : (M - 1);      // clamp: keep lanes active
      gld_lds16(A + (size_t)ga * K + k0 + q * 8, buf + sl * 16);
    }
  };
  auto stageB = [&](int slot, int kt) {
    char* buf = smem + (size_t)slot * SLOT + ASL * 16;
    int k0 = kt * 32;
    k0 = (k0 > K - 32) ? (K - 32) : k0;
#pragma unroll
    for (int i = 0; i < BSL / THREADS; ++i) {
      const int sl = i * THREADS + t;
      const int row = ((sl >> 6) << 4) + (sl & 15);
      const int q = (sl >> 4) & 3;
      gld_lds16(B + (size_t)(bn + row) * K + k0 + q * 8, buf + sl * 16);
    }
  };

  // prologue: tiles 0..DIST-1 in flight (DIST*LPT loads)
#pragma unroll
  for (int p = 0; p < DIST; ++p) {
    stageA(p, p);
    stageB(p, p);
  }

  const int NT = K >> 5;
  int cur = 0;
  for (int kt = 0; kt < NT; ++kt) {
    char* bufc = smem + (size_t)cur * SLOT;
    const int stg = (cur == 0) ? (RING - 1) : (cur - 1);
    // outstanding: DIST tiles (DIST*LPT). Wait for tile kt's LPT.
    if constexpr (WAITN == 8)
      asm volatile("s_waitcnt vmcnt(8)" ::: "memory");
    else if constexpr (WAITN == 6)
      asm volatile("s_waitcnt vmcnt(6)" ::: "memory");
    else
      asm volatile("s_waitcnt vmcnt(4)" ::: "memory");
    __builtin_amdgcn_s_barrier();  // slot[cur] ready AND slot[stg] consumed
    asm volatile("" ::: "memory");
    stageA(stg, kt + DIST);        // -> slot of tile kt-1, safe after barrier
    half8 fa[MI], fb[NI];
#pragma unroll
    for (int ni = 0; ni < NI; ++ni)
      fb[ni] = *(const half8*)(bufc + ASL * 16 + ((wc * NI + ni) << 10) + l * 16);
#pragma unroll
    for (int mi = 0; mi < MI / 2; ++mi)
      fa[mi] = *(const half8*)(bufc + ((wr * MI + mi) << 10) + l * 16);
    __builtin_amdgcn_s_setprio(1);
#pragma unroll
    for (int mi = 0; mi < MI / 2; ++mi)
#pragma unroll
      for (int ni = 0; ni < NI; ++ni)
        acc[mi][ni] = __builtin_amdgcn_mfma_f32_16x16x32_f16(
            fa[mi], fb[ni], acc[mi][ni], 0, 0, 0);
    __builtin_amdgcn_s_setprio(0);
    stageB(stg, kt + DIST);        // remaining loads of tile kt+DIST
#pragma unroll
    for (int mi = MI / 2; mi < MI; ++mi)
      fa[mi] = *(const half8*)(bufc + ((wr * MI + mi) << 10) + l * 16);
    __builtin_amdgcn_s_setprio(1);
#pragma unroll
    for (int mi = MI / 2; mi < MI; ++mi)
#pragma unroll
      for (int ni = 0; ni < NI; ++ni)
        acc[mi][ni] = __builtin_amdgcn_mfma_f32_16x16x32_f16(
            fa[mi], fb[ni], acc[mi][ni], 0, 0, 0);
    __builtin_amdgcn_s_setprio(0);
    cur = (cur == RING - 1) ? 0 : (cur + 1);
    // no end-of-tile barrier: distance-DIST ring tolerates the drift
  }
  asm volatile("s_waitcnt vmcnt(0)" ::: "memory");  // drain garbage prefetches
  // epilogue: C/D layout col=lane&15, row=quad*4+reg
  const int colbase = bn + wc * WTN + lrow;
#pragma unroll
  for (int mi = 0; mi < MI; ++mi) {
    const int rbase = bm + wr * WTM + mi * 16 + quad * 4;
#pragma unroll
    for (int r = 0; r < 4; ++r) {
      const int grow = rbase + r;
      if (grow < M) {
        if constexpr (OUTF16) {
          _Float16* C = (_Float16*)Cv;
#pragma unroll
          for (int ni = 0; ni < NI; ++ni)
            C[(size_t)grow * N + colbase + ni * 16] = (_Float16)acc[mi][ni][r];
        } else {
          float* C = (float*)Cv;
#pragma unroll
          for (int ni = 0; ni < NI; ++ni)
            C[(size_t)grow * N + colbase + ni * 16] = acc[mi][ni][r];
        }
      }
    }
  }
}

// ------- all three weight transposes + f16 casts (fallback path) ------
__global__ void wt_split_all(const float* __restrict__ W1, _Float16* Th1,
                             const float* __restrict__ W2, _Float16* Th2,
                             const float* __restrict__ W3, _Float16* Th3) {
  int idx = blockIdx.x * blockDim.x + threadIdx.x;
  const float* W;
  _Float16* Th;
  int K, N;
  if (idx < 64 * 512) {
    W = W1; Th = Th1; K = 64; N = 512;
  } else if (idx < 64 * 512 + 512 * 512) {
    idx -= 64 * 512;
    W = W2; Th = Th2; K = 512; N = 512;
  } else if (idx < 64 * 512 + 512 * 512 + 512 * 128) {
    idx -= 64 * 512 + 512 * 512;
    W = W3; Th = Th3; K = 512; N = 128;
  } else {
    return;
  }
  const int k = idx / N;
  const int n = idx - k * N;
  Th[n * K + k] = (_Float16)W[idx];
}

// --- combined prep: x casts + cnt=1 + total=0 + weight transposes -----
__global__ void prep_all(const float* __restrict__ x0, const float* __restrict__ x1,
                         _Float16* __restrict__ Xh, int* __restrict__ cnt,
                         int* __restrict__ total,
                         const float* __restrict__ W1, _Float16* Th1,
                         const float* __restrict__ W2, _Float16* Th2,
                         const float* __restrict__ W3, _Float16* Th3) {
  const int idx = blockIdx.x * blockDim.x + threadIdx.x;
  const int half = kN * 64;
  if (idx < half) {
    Xh[idx] = (_Float16)x0[idx];
  } else if (idx < 2 * half) {
    Xh[idx] = (_Float16)x1[idx - half];
  } else {
    int e = idx - 2 * half;
    const float* W;
    _Float16* Th;
    int K, N;
    if (e < 64 * 512) {
      W = W1; Th = Th1; K = 64; N = 512;
    } else if (e < 64 * 512 + 512 * 512) {
      e -= 64 * 512;
      W = W2; Th = Th2; K = 512; N = 512;
    } else if (e < 64 * 512 + 512 * 512 + 512 * 128) {
      e -= 64 * 512 + 512 * 512;
      W = W3; Th = Th3; K = 512; N = 128;
    } else {
      W = nullptr; Th = nullptr; K = N = 0;
    }
    if (W) {
      const int k = e / N;
      const int n = e - k * N;
      Th[n * K + k] = (_Float16)W[e];
    }
  }
  if (idx < 2 * kN) cnt[idx] = 1;  // the self loop
  if (idx == 0) *total = 0;
}
// ------- single-encoder prep (fallback path) --------------------------
__global__ void prep(const float* __restrict__ X, _Float16* __restrict__ Xh,
                     int* __restrict__ cnt, int* __restrict__ total, int nsplit,
                     int n) {
  const int idx = blockIdx.x * blockDim.x + threadIdx.x;
  if (idx < nsplit) Xh[idx] = (_Float16)X[idx];
  if (idx < n) cnt[idx] = 1;
  if (idx == 0) *total = 0;
}

// ---------------- CSR (by dst) build ----------------------------------
__global__ void count_edges2(const int* __restrict__ d0, const int* __restrict__ d1,
                             int* __restrict__ cnt) {
  const int i = blockIdx.x * blockDim.x + threadIdx.x;
  if (i < kE) atomicAdd(&cnt[d0[i]], 1);
  else if (i < 2 * kE) atomicAdd(&cnt[d1[i - kE] + kN], 1);
}
__global__ void fill_edges2(const int* __restrict__ s0, const int* __restrict__ d0,
                            const int* __restrict__ s1, const int* __restrict__ d1,
                            int* __restrict__ cursor, int* __restrict__ csr) {
  const int i = blockIdx.x * blockDim.x + threadIdx.x;
  if (i < kE) {
    const int p = atomicAdd(&cursor[d0[i]], 1);
    csr[p] = s0[i];
  } else if (i < 2 * kE) {
    const int j = i - kE;
    const int p = atomicAdd(&cursor[d1[j] + kN], 1);
    csr[p] = s1[j] + kN;
  }
}
__global__ void count_edges(const int* __restrict__ dst, int* __restrict__ cnt,
                            int ne) {
  const int i = blockIdx.x * blockDim.x + threadIdx.x;
  if (i < ne) atomicAdd(&cnt[dst[i]], 1);
}
__global__ void fill_edges(const int* __restrict__ src, const int* __restrict__ dst,
                           int* __restrict__ cursor, int* __restrict__ csr, int ne) {
  const int i = blockIdx.x * blockDim.x + threadIdx.x;
  if (i < ne) {
    const int p = atomicAdd(&cursor[dst[i]], 1);
    csr[p] = src[i];
  }
}
__global__ void alloc_ranges(const int* __restrict__ cnt, int* __restrict__ start,
                             int* __restrict__ cursor, int* __restrict__ total,
                             int* __restrict__ csr, int n) {
  const int i = blockIdx.x * blockDim.x + threadIdx.x;
  const int lane = threadIdx.x & 63;
  const int v = (i < n) ? cnt[i] : 0;
  int sc = v;
#pragma unroll
  for (int off = 1; off < 64; off <<= 1) {
    const int t = __shfl_up(sc, off);
    if (lane >= off) sc += t;
  }
  const int wtot = __shfl(sc, 63);
  int base = 0;
  if (lane == 63) base = atomicAdd(total, wtot);
  base = __shfl(base, 63);
  const int st = base + sc - v;
  if (i < n) {
    start[i] = st;
    cursor[i] = st + 1;
    csr[st] = i;  // self loop first
  }
}

// ---------------- GAT aggregate, layers 1-2 (f16 h) -------------------
// R19 form (verified best): TWO nodes per wave, interleaved — the serial
// chain is per-NODE (start/cnt -> csr idx -> gather); interleaving two
// nodes doubles every chain level in flight. R22's 4-node variant
// SPILLED (WRITE 297MB scratch) — ND=2 is the VGPR sweet spot.
__global__ void gat_agg4(const _Float16* __restrict__ h,
                         const float* __restrict__ a_src,
                         const float* __restrict__ a_dst,
                         const int* __restrict__ start, const int* __restrict__ cnt,
                         const int* __restrict__ csr_src,
                         const float* __restrict__ bias,
                         _Float16* __restrict__ outH, int n_nodes) {
  const int gtid = blockIdx.x * blockDim.x + threadIdx.x;
  const int wid = gtid >> 6;
  const int lane = threadIdx.x & 63;
  const int n0 = wid * 2;
  if (n0 >= n_nodes) return;
  const int n1r = (n0 + 1 < n_nodes) ? (n0 + 1) : n0;
  const bool has1 = (n0 + 1 < n_nodes);
  const int ch = lane * 8;
  float as_r[8], ad_r[8];
#pragma unroll
  for (int j = 0; j < 8; ++j) {
    as_r[j] = a_src[ch + j];
    ad_r[j] = a_dst[ch + j];
  }
  const int s0 = start[n0], c0 = cnt[n0];
  const int s1 = start[n1r];
  const int c1 = has1 ? cnt[n1r] : 0;
  // self gathers for both nodes (csr[s]==node; gives dst-dot + self edge)
  const half8 vsA = *(const half8*)(h + (size_t)n0 * 512 + ch);
  const half8 vsB = *(const half8*)(h + (size_t)n1r * 512 + ch);
  float fsA[8], fsB[8];
  float tAs = 0.f, tAd = 0.f, tBs = 0.f, tBd = 0.f;
#pragma unroll
  for (int j = 0; j < 8; ++j) {
    fsA[j] = (float)vsA[j];
    fsB[j] = (float)vsB[j];
    tAs = fmaf(fsA[j], as_r[j], tAs);
    tAd = fmaf(fsA[j], ad_r[j], tAd);
    tBs = fmaf(fsB[j], as_r[j], tBs);
    tBd = fmaf(fsB[j], ad_r[j], tBd);
  }
#pragma unroll
  for (int off = 1; off < 16; off <<= 1) {
    tAs += __shfl_xor(tAs, off);
    tAd += __shfl_xor(tAd, off);
    tBs += __shfl_xor(tBs, off);
    tBd += __shfl_xor(tBd, off);
  }
  const float adA = tAd, adB = tBd;
  float eA = tAs + adA, eB = tBs + adB;
  eA = (eA > 0.f) ? eA : kNegSlope * eA;
  eB = (eB > 0.f) ? eB : kNegSlope * eB;
  const float wsA = fexp(eA);
  const float wsB = fexp(eB);
  float dA = wsA, dB = wsB;
  float aA[8], aB[8];
#pragma unroll
  for (int j = 0; j < 8; ++j) {
    aA[j] = wsA * fsA[j];
    aB[j] = wsB * fsB[j];
  }
  const int cm = (c0 > c1) ? c0 : c1;
  int i = 1;
  for (; i + 2 <= cm; i += 2) {
    const int jA0 = (i < c0) ? i : 0, jA1 = (i + 1 < c0) ? i + 1 : 0;
    const int jB0 = (i < c1) ? i : 0, jB1 = (i + 1 < c1) ? i + 1 : 0;
    const int sA0 = csr_src[s0 + jA0];
    const int sA1 = csr_src[s0 + jA1];
    const int sB0 = csr_src[s1 + jB0];
    const int sB1 = csr_src[s1 + jB1];
    const half8 vA0 = *(const half8*)(h + (size_t)sA0 * 512 + ch);
    const half8 vA1 = *(const half8*)(h + (size_t)sA1 * 512 + ch);
    const half8 vB0 = *(const half8*)(h + (size_t)sB0 * 512 + ch);
    const half8 vB1 = *(const half8*)(h + (size_t)sB1 * 512 + ch);
    float fA0[8], fA1[8], fB0[8], fB1[8];
    float tA0 = 0.f, tA1 = 0.f, tB0 = 0.f, tB1 = 0.f;
#pragma unroll
    for (int j = 0; j < 8; ++j) {
      fA0[j] = (float)vA0[j]; tA0 = fmaf(fA0[j], as_r[j], tA0);
      fA1[j] = (float)vA1[j]; tA1 = fmaf(fA1[j], as_r[j], tA1);
      fB0[j] = (float)vB0[j]; tB0 = fmaf(fB0[j], as_r[j], tB0);
      fB1[j] = (float)vB1[j]; tB1 = fmaf(fB1[j], as_r[j], tB1);
    }
#pragma unroll
    for (int off = 1; off < 16; off <<= 1) {
      tA0 += __shfl_xor(tA0, off);
      tA1 += __shfl_xor(tA1, off);
      tB0 += __shfl_xor(tB0, off);
      tB1 += __shfl_xor(tB1, off);
    }
    float eA0 = tA0 + adA, eA1 = tA1 + adA;
    float eB0 = tB0 + adB, eB1 = tB1 + adB;
    eA0 = (eA0 > 0.f) ? eA0 : kNegSlope * eA0;
    eA1 = (eA1 > 0.f) ? eA1 : kNegSlope * eA1;
    eB0 = (eB0 > 0.f) ? eB0 : kNegSlope * eB0;
    eB1 = (eB1 > 0.f) ? eB1 : kNegSlope * eB1;
    const float wA0 = (i < c0) ? fexp(eA0) : 0.f;
    const float wA1 = (i + 1 < c0) ? fexp(eA1) : 0.f;
    const float wB0 = (i < c1) ? fexp(eB0) : 0.f;
    const float wB1 = (i + 1 < c1) ? fexp(eB1) : 0.f;
    dA += wA0 + wA1;
    dB += wB0 + wB1;
#pragma unroll
    for (int j = 0; j < 8; ++j) {
      aA[j] = fmaf(wA0, fA0[j], aA[j]);
      aA[j] = fmaf(wA1, fA1[j], aA[j]);
      aB[j] = fmaf(wB0, fB0[j], aB[j]);
      aB[j] = fmaf(wB1, fB1[j], aB[j]);
    }
  }
  if (i < cm) {  // tail: at most one edge per node
    const int jA = (i < c0) ? i : 0;
    const int jB = (i < c1) ? i : 0;
    const int sA = csr_src[s0 + jA];
    const int sB = csr_src[s1 + jB];
    const half8 vA = *(const half8*)(h + (size_t)sA * 512 + ch);
    const half8 vB = *(const half8*)(h + (size_t)sB * 512 + ch);
    float fA[8], fB[8];
    float tA = 0.f, tB = 0.f;
#pragma unroll
    for (int j = 0; j < 8; ++j) {
      fA[j] = (float)vA[j]; tA = fmaf(fA[j], as_r[j], tA);
      fB[j] = (float)vB[j]; tB = fmaf(fB[j], as_r[j], tB);
    }
#pragma unroll
    for (int off = 1; off < 16; off <<= 1) {
      tA += __shfl_xor(tA, off);
      tB += __shfl_xor(tB, off);
    }
    float eA2 = tA + adA, eB2 = tB + adB;
    eA2 = (eA2 > 0.f) ? eA2 : kNegSlope * eA2;
    eB2 = (eB2 > 0.f) ? eB2 : kNegSlope * eB2;
    const float wA = (i < c0) ? fexp(eA2) : 0.f;
    const float wB = (i < c1) ? fexp(eB2) : 0.f;
    dA += wA;
    dB += wB;
#pragma unroll
    for (int j = 0; j < 8; ++j) {
      aA[j] = fmaf(wA, fA[j], aA[j]);
      aB[j] = fmaf(wB, fB[j], aB[j]);
    }
  }
  const float invA = 1.f / (dA + 1e-16f);
  const float invB = 1.f / (dB + 1e-16f);
  half8 HA, HB;
#pragma unroll
  for (int j = 0; j < 8; ++j) {
    float vA = aA[j] * invA + bias[ch + j];
    vA = (vA > 0.f) ? vA : (fexp(vA) - 1.f);  // elu via hw exp
    HA[j] = (_Float16)vA;
    float vB = aB[j] * invB + bias[ch + j];
    vB = (vB > 0.f) ? vB : (fexp(vB) - 1.f);
    HB[j] = (_Float16)vB;
  }
  *(half8*)(outH + (size_t)n0 * 512 + ch) = HA;
  if (has1) *(half8*)(outH + (size_t)n1r * 512 + ch) = HB;
}

// ---------- GAT aggregate, layer 3 (H=1, f16 h, 2 nodes/wave) ---------
__global__ void gat_agg_l3(const _Float16* __restrict__ h,
                           const float* __restrict__ a_src,
                           const float* __restrict__ a_dst,
                           const int* __restrict__ start, const int* __restrict__ cnt,
                           const int* __restrict__ csr_src,
                           const float* __restrict__ bias,
                           float* __restrict__ out, int n_nodes) {
  const int gtid = blockIdx.x * blockDim.x + threadIdx.x;
  const int wid = gtid >> 6;
  const int lane = threadIdx.x & 63;
  const int n0 = wid * 2;
  if (n0 >= n_nodes) return;
  const int n1r = (n0 + 1 < n_nodes) ? (n0 + 1) : n0;
  const bool has1 = (n0 + 1 < n_nodes);
  const float2 asv = *(const float2*)(a_src + lane * 2);
  const float2 adv = *(const float2*)(a_dst + lane * 2);
  const int s0 = start[n0], c0 = cnt[n0];
  const int s1 = start[n1r];
  const int c1 = has1 ? cnt[n1r] : 0;
  // self gathers
  const half2v vsA = *(const half2v*)(h + (size_t)n0 * 128 + lane * 2);
  const half2v vsB = *(const half2v*)(h + (size_t)n1r * 128 + lane * 2);
  const float xA = (float)vsA[0], yA = (float)vsA[1];
  const float xB = (float)vsB[0], yB = (float)vsB[1];
  float tAs = fmaf(xA, asv.x, yA * asv.y);
  float tAd = fmaf(xA, adv.x, yA * adv.y);
  float tBs = fmaf(xB, asv.x, yB * asv.y);
  float tBd = fmaf(xB, adv.x, yB * adv.y);
#pragma unroll
  for (int off = 1; off < 64; off <<= 1) {
    tAs += __shfl_xor(tAs, off);
    tAd += __shfl_xor(tAd, off);
    tBs += __shfl_xor(tBs, off);
    tBd += __shfl_xor(tBd, off);
  }
  const float adA = tAd, adB = tBd;
  float eA = tAs + adA, eB = tBs + adB;
  eA = (eA > 0.f) ? eA : kNegSlope * eA;
  eB = (eB > 0.f) ? eB : kNegSlope * eB;
  const float wsA = fexp(eA);
  const float wsB = fexp(eB);
  float dA = wsA, dB = wsB;
  float2 aA = make_float2(wsA * xA, wsA * yA);
  float2 aB = make_float2(wsB * xB, wsB * yB);
  const int cm = (c0 > c1) ? c0 : c1;
  int i = 1;
  for (; i + 2 <= cm; i += 2) {
    const int jA0 = (i < c0) ? i : 0, jA1 = (i + 1 < c0) ? i + 1 : 0;
    const int jB0 = (i < c1) ? i : 0, jB1 = (i + 1 < c1) ? i + 1 : 0;
    const int sA0 = csr_src[s0 + jA0];
    const int sA1 = csr_src[s0 + jA1];
    const int sB0 = csr_src[s1 + jB0];
    const int sB1 = csr_src[s1 + jB1];
    const half2v vA0 = *(const half2v*)(h + (size_t)sA0 * 128 + lane * 2);
    const half2v vA1 = *(const half2v*)(h + (size_t)sA1 * 128 + lane * 2);
    const half2v vB0 = *(const half2v*)(h + (size_t)sB0 * 128 + lane * 2);
    const half2v vB1 = *(const half2v*)(h + (size_t)sB1 * 128 + lane * 2);
    const float xA0 = (float)vA0[0], yA0 = (float)vA0[1];
    const float xA1 = (float)vA1[0], yA1 = (float)vA1[1];
    const float xB0 = (float)vB0[0], yB0 = (float)vB0[1];
    const float xB1 = (float)vB1[0], yB1 = (float)vB1[1];
    float tA0 = fmaf(xA0, asv.x, yA0 * asv.y);
    float tA1 = fmaf(xA1, asv.x, yA1 * asv.y);
    float tB0 = fmaf(xB0, asv.x, yB0 * asv.y);
    float tB1 = fmaf(xB1, asv.x, yB1 * asv.y);
#pragma unroll
    for (int off = 1; off < 64; off <<= 1) {
      tA0 += __shfl_xor(tA0, off);
      tA1 += __shfl_xor(tA1, off);
      tB0 += __shfl_xor(tB0, off);
      tB1 += __shfl_xor(tB1, off);
    }
    float eA0 = tA0 + adA, eA1 = tA1 + adA;
    float eB0 = tB0 + adB, eB1 = tB1 + adB;
    eA0 = (eA0 > 0.f) ? eA0 : kNegSlope * eA0;
    eA1 = (eA1 > 0.f) ? eA1 : kNegSlope * eA1;
    eB0 = (eB0 > 0.f) ? eB0 : kNegSlope * eB0;
    eB1 = (eB1 > 0.f) ? eB1 : kNegSlope * eB1;
    const float wA0 = (i < c0) ? fexp(eA0) : 0.f;
    const float wA1 = (i + 1 < c0) ? fexp(eA1) : 0.f;
    const float wB0 = (i < c1) ? fexp(eB0) : 0.f;
    const float wB1 = (i + 1 < c1) ? fexp(eB1) : 0.f;
    dA += wA0 + wA1;
    dB += wB0 + wB1;
    aA.x = fmaf(wA0, xA0, aA.x); aA.x = fmaf(wA1, xA1, aA.x);
    aA.y = fmaf(wA0, yA0, aA.y); aA.y = fmaf(wA1, yA1, aA.y);
    aB.x = fmaf(wB0, xB0, aB.x); aB.x = fmaf(wB1, xB1, aB.x);
    aB.y = fmaf(wB0, yB0, aB.y); aB.y = fmaf(wB1, yB1, aB.y);
  }
  if (i < cm) {
    const int jA = (i < c0) ? i : 0;
    const int jB = (i < c1) ? i : 0;
    const int sA = csr_src[s0 + jA];
    const int sB = csr_src[s1 + jB];
    const half2v vA = *(const half2v*)(h + (size_t)sA * 128 + lane * 2);
    const half2v vB = *(const half2v*)(h + (size_t)sB * 128 + lane * 2);
    const float xA2 = (float)vA[0], yA2 = (float)vA[1];
    const float xB2 = (float)vB[0], yB2 = (float)vB[1];
    float tA = fmaf(xA2, asv.x, yA2 * asv.y);
    float tB = fmaf(xB2, asv.x, yB2 * asv.y);
#pragma unroll
    for (int off = 1; off < 64; off <<= 1) {
      tA += __shfl_xor(tA, off);
      tB += __shfl_xor(tB, off);
    }
    float eA2 = tA + adA, eB2 = tB + adB;
    eA2 = (eA2 > 0.f) ? eA2 : kNegSlope * eA2;
    eB2 = (eB2 > 0.f) ? eB2 : kNegSlope * eB2;
    const float wA = (i < c0) ? fexp(eA2) : 0.f;
    const float wB = (i < c1) ? fexp(eB2) : 0.f;
    dA += wA;
    dB += wB;
    aA.x = fmaf(wA, xA2, aA.x);
    aA.y = fmaf(wA, yA2, aA.y);
    aB.x = fmaf(wB, xB2, aB.x);
    aB.y = fmaf(wB, yB2, aB.y);
  }
  const float invA = 1.f / (dA + 1e-16f);
  const float invB = 1.f / (dB + 1e-16f);
  *(float2*)(out + (size_t)n0 * 128 + lane * 2) =
      make_float2(aA.x * invA + bias[lane * 2],
                  aA.y * invA + bias[lane * 2 + 1]);
  if (has1)
    *(float2*)(out + (size_t)n1r * 128 + lane * 2) =
        make_float2(aB.x * invB + bias[lane * 2],
                    aB.y * invB + bias[lane * 2 + 1]);
}

// ------- global max pool over sorted batch (both encoders, 1 launch) ---
__global__ void pool_max2(const float* __restrict__ x, const int* __restrict__ bt1,
                          const int* __restrict__ bt2, float* __restrict__ emb) {
  __shared__ int lohi[2];
  const int enc = blockIdx.x >> 8;
  const int g = blockIdx.x & 255;
  const int* batch = enc ? bt2 : bt1;
  const float* xx = x + (size_t)enc * kN * 128;
  if (threadIdx.x == 0) {
    int lo = 0, hi = kN;
    while (lo < hi) {
      const int mid = (lo + hi) >> 1;
      if (batch[mid] < g) lo = mid + 1; else hi = mid;
    }
    lohi[0] = lo;
    hi = kN;
    while (lo < hi) {
      const int mid = (lo + hi) >> 1;
      if (batch[mid] < g + 1) lo = mid + 1; else hi = mid;
    }
    lohi[1] = lo;
  }
  __syncthreads();
  const int lo = lohi[0], hi = lohi[1];
  const int c = threadIdx.x;  // 128 channels
  float m = -1e30f;
  for (int nid = lo; nid < hi; ++nid) m = fmaxf(m, xx[(size_t)nid * 128 + c]);
  emb[(size_t)blockIdx.x * 128 + c] = (lo < hi) ? m : 0.f;
}
// ------- single-encoder pool (fallback path) --------------------------
__global__ void pool_max(const float* __restrict__ x, const int* __restrict__ batch,
                         float* __restrict__ emb, int n_nodes) {
  __shared__ int lohi[2];
  const int g = blockIdx.x;
  if (threadIdx.x == 0) {
    int lo = 0, hi = n_nodes;
    while (lo < hi) {
      const int mid = (lo + hi) >> 1;
      if (batch[mid] < g) lo = mid + 1; else hi = mid;
    }
    lohi[0] = lo;
    hi = n_nodes;
    while (lo < hi) {
      const int mid = (lo + hi) >> 1;
      if (batch[mid] < g + 1) lo = mid + 1; else hi = mid;
    }
    lohi[1] = lo;
  }
  __syncthreads();
  const int lo = lohi[0], hi = lohi[1];
  const int c = threadIdx.x;  // 128 channels
  float m = -1e30f;
  for (int nid = lo; nid < hi; ++nid) m = fmaxf(m, x[(size_t)nid * 128 + c]);
  emb[g * 128 + c] = (lo < hi) ? m : 0.f;
}

// ---------------- final MLP head --------------------------------------
__global__ void mlp_head(const float* __restrict__ e1, const float* __restrict__ e2,
                         const float* __restrict__ mw1, const float* __restrict__ mb1,
                         const float* __restrict__ mw2, const float* __restrict__ mb2,
                         float* __restrict__ out) {
  __shared__ float z[256];
  __shared__ float red[128];
  const int g = blockIdx.x;
  const int j = threadIdx.x;  // 128
  z[j] = e1[g * 128 + j];
  z[j + 128] = e2[g * 128 + j];
  __syncthreads();
  float acc = mb1[j];
  for (int k = 0; k < 256; ++k) acc = fmaf(z[k], mw1[k * 128 + j], acc);
  acc = fmaxf(acc, 0.f) * mw2[j];
  red[j] = acc;
  __syncthreads();
  for (int s = 64; s > 0; s >>= 1) {
    if (j < s) red[j] += red[j + s];
    __syncthreads();
  }
  if (j == 0) out[g] = red[0] + mb2[0];
}

// ---------------- launcher --------------------------------------------
namespace {
struct Bufs {
  _Float16 *R1h, *R2h;
  float *R1f, *R2f, *asrc, *adst;
  int *cnt, *start, *cursor, *csr, *total;
  _Float16 *Wth1, *Wth2, *Wth3;
  float* emb;
  size_t need;
};

Bufs plan(void* d_ws, int M, int E) {
  Bufs b;
  char* w = (char*)d_ws;
  size_t off = 0;
  auto take = [&](size_t bytes) -> void* {
    void* p = w + off;
    off += (bytes + 255) & ~(size_t)255;
    return p;
  };
  b.R1h = (_Float16*)take((size_t)M * 512 * 2);  // f16 activations
  b.R1f = (float*)b.R1h;                         // layer-3 out alias [M,128]
  b.R2h = (_Float16*)take((size_t)M * 512 * 2);  // h f16 (l3 h f16 [M,128])
  b.R2f = (float*)b.R2h;
  b.asrc = (float*)take((size_t)M * 4 * 4);      // (kept for ws layout stability)
  b.adst = (float*)take((size_t)M * 4 * 4);
  b.cnt = (int*)take((size_t)M * 4);
  b.start = (int*)take((size_t)M * 4);
  b.cursor = (int*)take((size_t)M * 4);
  b.csr = (int*)take((size_t)E * 4);
  b.total = (int*)take(256);
  b.Wth1 = (_Float16*)take((size_t)64 * 512 * 2);
  b.Wth2 = (_Float16*)take((size_t)512 * 512 * 2);
  b.Wth3 = (_Float16*)take((size_t)512 * 128 * 2);
  b.emb = (float*)take((size_t)2 * kG * 128 * 4);
  b.need = off;
  return b;
}

void run_layers(const Bufs& b, void* const* d_in, int M, hipStream_t stream) {
  const float* as1 = (const float*)d_in[7];
  const float* ad1 = (const float*)d_in[8];
  const float* b1 = (const float*)d_in[9];
  const float* as2 = (const float*)d_in[11];
  const float* ad2 = (const float*)d_in[12];
  const float* b2 = (const float*)d_in[13];
  const float* as3 = (const float*)d_in[15];
  const float* ad3 = (const float*)d_in[16];
  const float* b3 = (const float*)d_in[17];
  const int aggBlocks = (((M + 1) / 2) * 64 + 255) / 256;  // 2 nodes/wave
  const int RT128 = (M + 127) / 128;
  const int SP128 = (RT128 + 7) / 8;      // 128-row tile groups (XCD map)
  const int RT256 = (M + 255) / 256;
  const int SP256 = (RT256 + 7) / 8;      // 256-row tile groups

  // layer 1: [M,64] @ [64,512], BM=128 (K=64: small tile wins — R9)
  gemm_ring<1, 128, 256, 2><<<SP128 * 16, 256, 0, stream>>>(b.R1h, b.Wth1, b.R2h,
                                                            M, 512, 64);
  gat_agg4<<<aggBlocks, 256, 0, stream>>>(b.R2h, as1, ad1, b.start, b.cnt,
                                          b.csr, b1, b.R1h, M);
  // layer 2: [M,512] @ [512,512], BM=256 (best measured config — R8)
  gemm_ring<1, 256, 256, 2><<<SP256 * 16, 512, 0, stream>>>(b.R1h, b.Wth2, b.R2h,
                                                            M, 512, 512);
  gat_agg4<<<aggBlocks, 256, 0, stream>>>(b.R2h, as2, ad2, b.start, b.cnt,
                                          b.csr, b2, b.R1h, M);
  // layer 3: [M,512] @ [512,128], BM=128, h -> f16
  gemm_ring<1, 128, 128, 1><<<SP128 * 8, 256, 0, stream>>>(b.R1h, b.Wth3, b.R2h,
                                                           M, 128, 512);
  gat_agg_l3<<<aggBlocks, 256, 0, stream>>>(b.R2h, as3, ad3, b.start, b.cnt,
                                            b.csr, b3, b.R1f, M);
}
}  // namespace

extern "C" void kernel_launch(void* const* d_in, const int* in_sizes, int n_in,
                              void* d_out, int out_size, void* d_ws, size_t ws_size,
                              hipStream_t stream) {
  (void)in_sizes; (void)n_in; (void)out_size;
  const float* W1 = (const float*)d_in[6];
  const float* W2 = (const float*)d_in[10];
  const float* W3 = (const float*)d_in[14];
  const float* mw1 = (const float*)d_in[18];
  const float* mb1 = (const float*)d_in[19];
  const float* mw2 = (const float*)d_in[20];
  const float* mb2 = (const float*)d_in[21];

  // Prefer combined (both encoders batched, M=2N) if it fits the workspace.
  Bufs bc = plan(d_ws, 2 * kN, 2 * kE2);
  const bool combined = bc.need <= ws_size;
  Bufs b = combined ? bc : plan(d_ws, kN, kE2);

  const int wtot = 64 * 512 + 512 * 512 + 512 * 128;
  if (combined) {
    const int M = 2 * kN;
    const int* ei0 = (const int*)d_in[1];
    const int* ei1 = (const int*)d_in[4];
    prep_all<<<(M * 64 + wtot + 255) / 256, 256, 0, stream>>>(
        (const float*)d_in[0], (const float*)d_in[3], b.R1h, b.cnt, b.total,
        W1, b.Wth1, W2, b.Wth2, W3, b.Wth3);
    count_edges2<<<(2 * kE + 255) / 256, 256, 0, stream>>>(ei0 + kE, ei1 + kE,
                                                           b.cnt);
    alloc_ranges<<<(M + 255) / 256, 256, 0, stream>>>(b.cnt, b.start, b.cursor,
                                                      b.total, b.csr, M);
    fill_edges2<<<(2 * kE + 255) / 256, 256, 0, stream>>>(ei0, ei0 + kE, ei1,
                                                          ei1 + kE, b.cursor, b.csr);
    run_layers(b, d_in, M, stream);
    pool_max2<<<2 * kG, 128, 0, stream>>>(b.R1f, (const int*)d_in[2],
                                          (const int*)d_in[5], b.emb);
  } else {
    wt_split_all<<<(wtot + 255) / 256, 256, 0, stream>>>(W1, b.Wth1, W2, b.Wth2,
                                                         W3, b.Wth3);
    for (int enc = 0; enc < 2; ++enc) {
      const float* x = (const float*)d_in[enc * 3 + 0];
      const int* ei = (const int*)d_in[enc * 3 + 1];
      const int* batch = (const int*)d_in[enc * 3 + 2];
      prep<<<(kN * 64 + 255) / 256, 256, 0, stream>>>(x, b.R1h, b.cnt, b.total,
                                                      kN * 64, kN);
      count_edges<<<(kE + 255) / 256, 256, 0, stream>>>(ei + kE, b.cnt, kE);
      alloc_ranges<<<(kN + 255) / 256, 256, 0, stream>>>(b.cnt, b.start, b.cursor,
                                                         b.total, b.csr, kN);
      fill_edges<<<(kE + 255) / 256, 256, 0, stream>>>(ei, ei + kE, b.cursor, b.csr,
                                                       kE);
      run_layers(b, d_in, kN, stream);
      pool_max<<<kG, 128, 0, stream>>>(b.R1f, batch, b.emb + (size_t)enc * kG * 128,
                                       kN);
    }
  }
  mlp_head<<<kG, 128, 0, stream>>>(b.emb, b.emb + (size_t)kG * 128, mw1, mb1, mw2,
                                   mb2, (float*)d_out);
}

// Round 12
// 621.852 us; speedup vs baseline: 1.4312x; 1.0186x over previous
//
#include <hip/hip_runtime.h>
#include <cstdint>

namespace {
constexpr int kN = 50000;          // nodes per encoder
constexpr int kE = 200000;         // directed edges per encoder (pre self-loop)
constexpr int kE2 = kE + kN;       // with self loops (per encoder)
constexpr int kG = 256;            // graphs per encoder
constexpr float kNegSlope = 0.2f;
}

using half8   = __attribute__((ext_vector_type(8))) _Float16;
using half2v  = __attribute__((ext_vector_type(2))) _Float16;
using floatx4 = __attribute__((ext_vector_type(4))) float;

__device__ __forceinline__ void gld_lds16(const void* g, void* l) {
  __builtin_amdgcn_global_load_lds(
      (const __attribute__((address_space(1))) unsigned int*)g,
      (__attribute__((address_space(3))) unsigned int*)l, 16, 0, 0);
}

// fast exp: e^x = 2^(x*log2(e)) via hardware v_exp_f32 (no libm call)
__device__ __forceinline__ float fexp(float x) {
  return __builtin_amdgcn_exp2f(x * 1.44269504088896f);
}

// ---------------- fp16 MFMA GEMM: C[M,N] = A[M,K] @ B[K,N] -----------
// R24 l2 variant: BM=256/BN=256, BK=32, RING=2 (2x32KB = 64KB LDS) ->
// TWO blocks/CU. R11 showed l2 at 1 block/CU sustains only 4.1 TB/s on
// the global->LDS staging path (LDS 128KB was the occupancy cap, not
// VGPRs: 92V+128A=220 <= 512/wave at 4 waves/SIMD). Doubling resident
// blocks doubles staging-path occupancy and refines the 4-round
// makespan tail. Distance-1 ring REQUIRES two barriers per tile (a
// lagging wave may not have ds_read tile kt-1 when slot is re-staged);
// counted vmcnt(LPT) keeps next tile's loads in flight across both.
template <int OUTF16, int BM, int BN, int CT, int RING>
__global__ __launch_bounds__((BM == 256) ? 512 : 256, 2) void gemm_ring(
    const _Float16* __restrict__ A, const _Float16* __restrict__ B,
    void* __restrict__ Cv, int M, int N, int K) {
  constexpr int THREADS = (BM == 256) ? 512 : 256;
  constexpr int ASL = BM * 4;              // A slots/tile (16B each)
  constexpr int BSL = BN * 4;              // B slots/tile
  constexpr int SLOT = (ASL + BSL) * 16;
  constexpr int LPT = (ASL + BSL) / THREADS;
  constexpr int DIST = RING - 1;
  constexpr int WAITN = (RING == 2) ? LPT : (DIST - 1) * LPT;
  constexpr int WAVES = THREADS / 64;
  constexpr int WN = (BM == 256) ? 4 : 2;
  constexpr int WM = WAVES / WN;           // 2
  constexpr int WTM = BM / WM;             // 128 or 64
  constexpr int WTN = BN / WN;             // 64 or 128
  constexpr int MI = WTM / 16;
  constexpr int NI = WTN / 16;
  __shared__ alignas(16) char smem[RING * SLOT];
  const int t = threadIdx.x;
  const int w = t >> 6, l = t & 63;
  const int x = blockIdx.x & 7, s = blockIdx.x >> 3;
  const int col = (CT == 1) ? 0 : (s & (CT - 1));
  const int rt = ((CT == 1) ? s : (s >> 1)) * 8 + x;
  const int bm = rt * BM;
  const int bn = col * BN;
  if (bm >= M) return;  // padded row-tiles: whole block exits (no barrier)
  const int wr = w / WN, wc = w % WN;
  const int quad = l >> 4, lrow = l & 15;

  floatx4 acc[MI][NI];
#pragma unroll
  for (int mi = 0; mi < MI; ++mi)
#pragma unroll
    for (int ni = 0; ni < NI; ++ni) acc[mi][ni] = (floatx4){0.f, 0.f, 0.f, 0.f};

  // stage tile kt's A-part / B-part into the given ring slot
  auto stageA = [&](int slot, int kt) {
    char* buf = smem + (size_t)slot * SLOT;
    int k0 = kt * 32;
    k0 = (k0 > K - 32) ? (K - 32) : k0;  // clamp: beyond-NT garbage stays in-bounds
#pragma unroll
    for (int i = 0; i < ASL / THREADS; ++i) {
      const int sl = i * THREADS + t;
      const int row = ((sl >> 6) << 4) + (sl & 15);
      const int q = (sl >> 4) & 3;
      int ga = bm + row;
      ga = (ga < M) ? ga : (M - 1);      // clamp: keep lanes active
      gld_lds16(A + (size_t)ga * K + k0 + q * 8, buf + sl * 16);
    }
  };
  auto stageB = [&](int slot, int kt) {
    char* buf = smem + (size_t)slot * SLOT + ASL * 16;
    int k0 = kt * 32;
    k0 = (k0 > K - 32) ? (K - 32) : k0;
#pragma unroll
    for (int i = 0; i < BSL / THREADS; ++i) {
      const int sl = i * THREADS + t;
      const int row = ((sl >> 6) << 4) + (sl & 15);
      const int q = (sl >> 4) & 3;
      gld_lds16(B + (size_t)(bn + row) * K + k0 + q * 8, buf + sl * 16);
    }
  };

  // prologue: tiles 0..DIST-1 in flight
#pragma unroll
  for (int p = 0; p < DIST; ++p) {
    stageA(p, p);
    stageB(p, p);
  }

  const int NT = K >> 5;
  int cur = 0;
  for (int kt = 0; kt < NT; ++kt) {
    char* bufc = smem + (size_t)cur * SLOT;
    if constexpr (RING == 2) {
      // dist-1 double buffer: stage kt+1 FIRST (into slot cur^1, still
      // holding kt-1 — guarded by the END barrier of iteration kt-1),
      // counted wait for kt's loads, barrier, compute, end barrier.
      stageA(cur ^ 1, kt + 1);
      stageB(cur ^ 1, kt + 1);
      asm volatile("s_waitcnt vmcnt(4)" ::: "memory");  // kt's LPT landed
      __builtin_amdgcn_s_barrier();
      asm volatile("" ::: "memory");
      half8 fa[MI], fb[NI];
#pragma unroll
      for (int ni = 0; ni < NI; ++ni)
        fb[ni] = *(const half8*)(bufc + ASL * 16 + ((wc * NI + ni) << 10) + l * 16);
#pragma unroll
      for (int mi = 0; mi < MI; ++mi)
        fa[mi] = *(const half8*)(bufc + ((wr * MI + mi) << 10) + l * 16);
      __builtin_amdgcn_s_setprio(1);
#pragma unroll
      for (int mi = 0; mi < MI; ++mi)
#pragma unroll
        for (int ni = 0; ni < NI; ++ni)
          acc[mi][ni] = __builtin_amdgcn_mfma_f32_16x16x32_f16(
              fa[mi], fb[ni], acc[mi][ni], 0, 0, 0);
      __builtin_amdgcn_s_setprio(0);
      asm volatile("" ::: "memory");
      __builtin_amdgcn_s_barrier();  // slot[cur] free for re-staging
      cur ^= 1;
    } else {
      const int stg = (cur == 0) ? (RING - 1) : (cur - 1);
      if constexpr (WAITN == 8)
        asm volatile("s_waitcnt vmcnt(8)" ::: "memory");
      else if constexpr (WAITN == 6)
        asm volatile("s_waitcnt vmcnt(6)" ::: "memory");
      else
        asm volatile("s_waitcnt vmcnt(4)" ::: "memory");
      __builtin_amdgcn_s_barrier();  // slot[cur] ready AND slot[stg] consumed
      asm volatile("" ::: "memory");
      stageA(stg, kt + DIST);        // -> slot of tile kt-1, safe after barrier
      half8 fa[MI], fb[NI];
#pragma unroll
      for (int ni = 0; ni < NI; ++ni)
        fb[ni] = *(const half8*)(bufc + ASL * 16 + ((wc * NI + ni) << 10) + l * 16);
#pragma unroll
      for (int mi = 0; mi < MI / 2; ++mi)
        fa[mi] = *(const half8*)(bufc + ((wr * MI + mi) << 10) + l * 16);
      __builtin_amdgcn_s_setprio(1);
#pragma unroll
      for (int mi = 0; mi < MI / 2; ++mi)
#pragma unroll
        for (int ni = 0; ni < NI; ++ni)
          acc[mi][ni] = __builtin_amdgcn_mfma_f32_16x16x32_f16(
              fa[mi], fb[ni], acc[mi][ni], 0, 0, 0);
      __builtin_amdgcn_s_setprio(0);
      stageB(stg, kt + DIST);        // remaining loads of tile kt+DIST
#pragma unroll
      for (int mi = MI / 2; mi < MI; ++mi)
        fa[mi] = *(const half8*)(bufc + ((wr * MI + mi) << 10) + l * 16);
      __builtin_amdgcn_s_setprio(1);
#pragma unroll
      for (int mi = MI / 2; mi < MI; ++mi)
#pragma unroll
        for (int ni = 0; ni < NI; ++ni)
          acc[mi][ni] = __builtin_amdgcn_mfma_f32_16x16x32_f16(
              fa[mi], fb[ni], acc[mi][ni], 0, 0, 0);
      __builtin_amdgcn_s_setprio(0);
      cur = (cur == RING - 1) ? 0 : (cur + 1);
      // no end-of-tile barrier: distance-DIST ring tolerates the drift
    }
  }
  asm volatile("s_waitcnt vmcnt(0)" ::: "memory");  // drain garbage prefetches
  // epilogue: C/D layout col=lane&15, row=quad*4+reg
  const int colbase = bn + wc * WTN + lrow;
#pragma unroll
  for (int mi = 0; mi < MI; ++mi) {
    const int rbase = bm + wr * WTM + mi * 16 + quad * 4;
#pragma unroll
    for (int r = 0; r < 4; ++r) {
      const int grow = rbase + r;
      if (grow < M) {
        if constexpr (OUTF16) {
          _Float16* C = (_Float16*)Cv;
#pragma unroll
          for (int ni = 0; ni < NI; ++ni)
            C[(size_t)grow * N + colbase + ni * 16] = (_Float16)acc[mi][ni][r];
        } else {
          float* C = (float*)Cv;
#pragma unroll
          for (int ni = 0; ni < NI; ++ni)
            C[(size_t)grow * N + colbase + ni * 16] = acc[mi][ni][r];
        }
      }
    }
  }
}

// ------- all three weight transposes + f16 casts (fallback path) ------
__global__ void wt_split_all(const float* __restrict__ W1, _Float16* Th1,
                             const float* __restrict__ W2, _Float16* Th2,
                             const float* __restrict__ W3, _Float16* Th3) {
  int idx = blockIdx.x * blockDim.x + threadIdx.x;
  const float* W;
  _Float16* Th;
  int K, N;
  if (idx < 64 * 512) {
    W = W1; Th = Th1; K = 64; N = 512;
  } else if (idx < 64 * 512 + 512 * 512) {
    idx -= 64 * 512;
    W = W2; Th = Th2; K = 512; N = 512;
  } else if (idx < 64 * 512 + 512 * 512 + 512 * 128) {
    idx -= 64 * 512 + 512 * 512;
    W = W3; Th = Th3; K = 512; N = 128;
  } else {
    return;
  }
  const int k = idx / N;
  const int n = idx - k * N;
  Th[n * K + k] = (_Float16)W[idx];
}

// --- combined prep: x casts + cnt=1 + total=0 + weight transposes -----
__global__ void prep_all(const float* __restrict__ x0, const float* __restrict__ x1,
                         _Float16* __restrict__ Xh, int* __restrict__ cnt,
                         int* __restrict__ total,
                         const float* __restrict__ W1, _Float16* Th1,
                         const float* __restrict__ W2, _Float16* Th2,
                         const float* __restrict__ W3, _Float16* Th3) {
  const int idx = blockIdx.x * blockDim.x + threadIdx.x;
  const int half = kN * 64;
  if (idx < half) {
    Xh[idx] = (_Float16)x0[idx];
  } else if (idx < 2 * half) {
    Xh[idx] = (_Float16)x1[idx - half];
  } else {
    int e = idx - 2 * half;
    const float* W;
    _Float16* Th;
    int K, N;
    if (e < 64 * 512) {
      W = W1; Th = Th1; K = 64; N = 512;
    } else if (e < 64 * 512 + 512 * 512) {
      e -= 64 * 512;
      W = W2; Th = Th2; K = 512; N = 512;
    } else if (e < 64 * 512 + 512 * 512 + 512 * 128) {
      e -= 64 * 512 + 512 * 512;
      W = W3; Th = Th3; K = 512; N = 128;
    } else {
      W = nullptr; Th = nullptr; K = N = 0;
    }
    if (W) {
      const int k = e / N;
      const int n = e - k * N;
      Th[n * K + k] = (_Float16)W[e];
    }
  }
  if (idx < 2 * kN) cnt[idx] = 1;  // the self loop
  if (idx == 0) *total = 0;
}
// ------- single-encoder prep (fallback path) --------------------------
__global__ void prep(const float* __restrict__ X, _Float16* __restrict__ Xh,
                     int* __restrict__ cnt, int* __restrict__ total, int nsplit,
                     int n) {
  const int idx = blockIdx.x * blockDim.x + threadIdx.x;
  if (idx < nsplit) Xh[idx] = (_Float16)X[idx];
  if (idx < n) cnt[idx] = 1;
  if (idx == 0) *total = 0;
}

// ---------------- CSR (by dst) build ----------------------------------
__global__ void count_edges2(const int* __restrict__ d0, const int* __restrict__ d1,
                             int* __restrict__ cnt) {
  const int i = blockIdx.x * blockDim.x + threadIdx.x;
  if (i < kE) atomicAdd(&cnt[d0[i]], 1);
  else if (i < 2 * kE) atomicAdd(&cnt[d1[i - kE] + kN], 1);
}
__global__ void fill_edges2(const int* __restrict__ s0, const int* __restrict__ d0,
                            const int* __restrict__ s1, const int* __restrict__ d1,
                            int* __restrict__ cursor, int* __restrict__ csr) {
  const int i = blockIdx.x * blockDim.x + threadIdx.x;
  if (i < kE) {
    const int p = atomicAdd(&cursor[d0[i]], 1);
    csr[p] = s0[i];
  } else if (i < 2 * kE) {
    const int j = i - kE;
    const int p = atomicAdd(&cursor[d1[j] + kN], 1);
    csr[p] = s1[j] + kN;
  }
}
__global__ void count_edges(const int* __restrict__ dst, int* __restrict__ cnt,
                            int ne) {
  const int i = blockIdx.x * blockDim.x + threadIdx.x;
  if (i < ne) atomicAdd(&cnt[dst[i]], 1);
}
__global__ void fill_edges(const int* __restrict__ src, const int* __restrict__ dst,
                           int* __restrict__ cursor, int* __restrict__ csr, int ne) {
  const int i = blockIdx.x * blockDim.x + threadIdx.x;
  if (i < ne) {
    const int p = atomicAdd(&cursor[dst[i]], 1);
    csr[p] = src[i];
  }
}
__global__ void alloc_ranges(const int* __restrict__ cnt, int* __restrict__ start,
                             int* __restrict__ cursor, int* __restrict__ total,
                             int* __restrict__ csr, int n) {
  const int i = blockIdx.x * blockDim.x + threadIdx.x;
  const int lane = threadIdx.x & 63;
  const int v = (i < n) ? cnt[i] : 0;
  int sc = v;
#pragma unroll
  for (int off = 1; off < 64; off <<= 1) {
    const int t = __shfl_up(sc, off);
    if (lane >= off) sc += t;
  }
  const int wtot = __shfl(sc, 63);
  int base = 0;
  if (lane == 63) base = atomicAdd(total, wtot);
  base = __shfl(base, 63);
  const int st = base + sc - v;
  if (i < n) {
    start[i] = st;
    cursor[i] = st + 1;
    csr[st] = i;  // self loop first
  }
}

// ---------------- GAT aggregate, layers 1-2 (f16 h) -------------------
// R19 form (verified best): TWO nodes per wave, interleaved — the serial
// chain is per-NODE (start/cnt -> csr idx -> gather); interleaving two
// nodes doubles every chain level in flight. 4-node variant SPILLED.
__global__ void gat_agg4(const _Float16* __restrict__ h,
                         const float* __restrict__ a_src,
                         const float* __restrict__ a_dst,
                         const int* __restrict__ start, const int* __restrict__ cnt,
                         const int* __restrict__ csr_src,
                         const float* __restrict__ bias,
                         _Float16* __restrict__ outH, int n_nodes) {
  const int gtid = blockIdx.x * blockDim.x + threadIdx.x;
  const int wid = gtid >> 6;
  const int lane = threadIdx.x & 63;
  const int n0 = wid * 2;
  if (n0 >= n_nodes) return;
  const int n1r = (n0 + 1 < n_nodes) ? (n0 + 1) : n0;
  const bool has1 = (n0 + 1 < n_nodes);
  const int ch = lane * 8;
  float as_r[8], ad_r[8];
#pragma unroll
  for (int j = 0; j < 8; ++j) {
    as_r[j] = a_src[ch + j];
    ad_r[j] = a_dst[ch + j];
  }
  const int s0 = start[n0], c0 = cnt[n0];
  const int s1 = start[n1r];
  const int c1 = has1 ? cnt[n1r] : 0;
  // self gathers for both nodes (csr[s]==node; gives dst-dot + self edge)
  const half8 vsA = *(const half8*)(h + (size_t)n0 * 512 + ch);
  const half8 vsB = *(const half8*)(h + (size_t)n1r * 512 + ch);
  float fsA[8], fsB[8];
  float tAs = 0.f, tAd = 0.f, tBs = 0.f, tBd = 0.f;
#pragma unroll
  for (int j = 0; j < 8; ++j) {
    fsA[j] = (float)vsA[j];
    fsB[j] = (float)vsB[j];
    tAs = fmaf(fsA[j], as_r[j], tAs);
    tAd = fmaf(fsA[j], ad_r[j], tAd);
    tBs = fmaf(fsB[j], as_r[j], tBs);
    tBd = fmaf(fsB[j], ad_r[j], tBd);
  }
#pragma unroll
  for (int off = 1; off < 16; off <<= 1) {
    tAs += __shfl_xor(tAs, off);
    tAd += __shfl_xor(tAd, off);
    tBs += __shfl_xor(tBs, off);
    tBd += __shfl_xor(tBd, off);
  }
  const float adA = tAd, adB = tBd;
  float eA = tAs + adA, eB = tBs + adB;
  eA = (eA > 0.f) ? eA : kNegSlope * eA;
  eB = (eB > 0.f) ? eB : kNegSlope * eB;
  const float wsA = fexp(eA);
  const float wsB = fexp(eB);
  float dA = wsA, dB = wsB;
  float aA[8], aB[8];
#pragma unroll
  for (int j = 0; j < 8; ++j) {
    aA[j] = wsA * fsA[j];
    aB[j] = wsB * fsB[j];
  }
  const int cm = (c0 > c1) ? c0 : c1;
  int i = 1;
  for (; i + 2 <= cm; i += 2) {
    const int jA0 = (i < c0) ? i : 0, jA1 = (i + 1 < c0) ? i + 1 : 0;
    const int jB0 = (i < c1) ? i : 0, jB1 = (i + 1 < c1) ? i + 1 : 0;
    const int sA0 = csr_src[s0 + jA0];
    const int sA1 = csr_src[s0 + jA1];
    const int sB0 = csr_src[s1 + jB0];
    const int sB1 = csr_src[s1 + jB1];
    const half8 vA0 = *(const half8*)(h + (size_t)sA0 * 512 + ch);
    const half8 vA1 = *(const half8*)(h + (size_t)sA1 * 512 + ch);
    const half8 vB0 = *(const half8*)(h + (size_t)sB0 * 512 + ch);
    const half8 vB1 = *(const half8*)(h + (size_t)sB1 * 512 + ch);
    float fA0[8], fA1[8], fB0[8], fB1[8];
    float tA0 = 0.f, tA1 = 0.f, tB0 = 0.f, tB1 = 0.f;
#pragma unroll
    for (int j = 0; j < 8; ++j) {
      fA0[j] = (float)vA0[j]; tA0 = fmaf(fA0[j], as_r[j], tA0);
      fA1[j] = (float)vA1[j]; tA1 = fmaf(fA1[j], as_r[j], tA1);
      fB0[j] = (float)vB0[j]; tB0 = fmaf(fB0[j], as_r[j], tB0);
      fB1[j] = (float)vB1[j]; tB1 = fmaf(fB1[j], as_r[j], tB1);
    }
#pragma unroll
    for (int off = 1; off < 16; off <<= 1) {
      tA0 += __shfl_xor(tA0, off);
      tA1 += __shfl_xor(tA1, off);
      tB0 += __shfl_xor(tB0, off);
      tB1 += __shfl_xor(tB1, off);
    }
    float eA0 = tA0 + adA, eA1 = tA1 + adA;
    float eB0 = tB0 + adB, eB1 = tB1 + adB;
    eA0 = (eA0 > 0.f) ? eA0 : kNegSlope * eA0;
    eA1 = (eA1 > 0.f) ? eA1 : kNegSlope * eA1;
    eB0 = (eB0 > 0.f) ? eB0 : kNegSlope * eB0;
    eB1 = (eB1 > 0.f) ? eB1 : kNegSlope * eB1;
    const float wA0 = (i < c0) ? fexp(eA0) : 0.f;
    const float wA1 = (i + 1 < c0) ? fexp(eA1) : 0.f;
    const float wB0 = (i < c1) ? fexp(eB0) : 0.f;
    const float wB1 = (i + 1 < c1) ? fexp(eB1) : 0.f;
    dA += wA0 + wA1;
    dB += wB0 + wB1;
#pragma unroll
    for (int j = 0; j < 8; ++j) {
      aA[j] = fmaf(wA0, fA0[j], aA[j]);
      aA[j] = fmaf(wA1, fA1[j], aA[j]);
      aB[j] = fmaf(wB0, fB0[j], aB[j]);
      aB[j] = fmaf(wB1, fB1[j], aB[j]);
    }
  }
  if (i < cm) {  // tail: at most one edge per node
    const int jA = (i < c0) ? i : 0;
    const int jB = (i < c1) ? i : 0;
    const int sA = csr_src[s0 + jA];
    const int sB = csr_src[s1 + jB];
    const half8 vA = *(const half8*)(h + (size_t)sA * 512 + ch);
    const half8 vB = *(const half8*)(h + (size_t)sB * 512 + ch);
    float fA[8], fB[8];
    float tA = 0.f, tB = 0.f;
#pragma unroll
    for (int j = 0; j < 8; ++j) {
      fA[j] = (float)vA[j]; tA = fmaf(fA[j], as_r[j], tA);
      fB[j] = (float)vB[j]; tB = fmaf(fB[j], as_r[j], tB);
    }
#pragma unroll
    for (int off = 1; off < 16; off <<= 1) {
      tA += __shfl_xor(tA, off);
      tB += __shfl_xor(tB, off);
    }
    float eA2 = tA + adA, eB2 = tB + adB;
    eA2 = (eA2 > 0.f) ? eA2 : kNegSlope * eA2;
    eB2 = (eB2 > 0.f) ? eB2 : kNegSlope * eB2;
    const float wA = (i < c0) ? fexp(eA2) : 0.f;
    const float wB = (i < c1) ? fexp(eB2) : 0.f;
    dA += wA;
    dB += wB;
#pragma unroll
    for (int j = 0; j < 8; ++j) {
      aA[j] = fmaf(wA, fA[j], aA[j]);
      aB[j] = fmaf(wB, fB[j], aB[j]);
    }
  }
  const float invA = 1.f / (dA + 1e-16f);
  const float invB = 1.f / (dB + 1e-16f);
  half8 HA, HB;
#pragma unroll
  for (int j = 0; j < 8; ++j) {
    float vA = aA[j] * invA + bias[ch + j];
    vA = (vA > 0.f) ? vA : (fexp(vA) - 1.f);  // elu via hw exp
    HA[j] = (_Float16)vA;
    float vB = aB[j] * invB + bias[ch + j];
    vB = (vB > 0.f) ? vB : (fexp(vB) - 1.f);
    HB[j] = (_Float16)vB;
  }
  *(half8*)(outH + (size_t)n0 * 512 + ch) = HA;
  if (has1) *(half8*)(outH + (size_t)n1r * 512 + ch) = HB;
}

// ---------- GAT aggregate, layer 3 (H=1, f16 h, 2 nodes/wave) ---------
__global__ void gat_agg_l3(const _Float16* __restrict__ h,
                           const float* __restrict__ a_src,
                           const float* __restrict__ a_dst,
                           const int* __restrict__ start, const int* __restrict__ cnt,
                           const int* __restrict__ csr_src,
                           const float* __restrict__ bias,
                           float* __restrict__ out, int n_nodes) {
  const int gtid = blockIdx.x * blockDim.x + threadIdx.x;
  const int wid = gtid >> 6;
  const int lane = threadIdx.x & 63;
  const int n0 = wid * 2;
  if (n0 >= n_nodes) return;
  const int n1r = (n0 + 1 < n_nodes) ? (n0 + 1) : n0;
  const bool has1 = (n0 + 1 < n_nodes);
  const float2 asv = *(const float2*)(a_src + lane * 2);
  const float2 adv = *(const float2*)(a_dst + lane * 2);
  const int s0 = start[n0], c0 = cnt[n0];
  const int s1 = start[n1r];
  const int c1 = has1 ? cnt[n1r] : 0;
  // self gathers
  const half2v vsA = *(const half2v*)(h + (size_t)n0 * 128 + lane * 2);
  const half2v vsB = *(const half2v*)(h + (size_t)n1r * 128 + lane * 2);
  const float xA = (float)vsA[0], yA = (float)vsA[1];
  const float xB = (float)vsB[0], yB = (float)vsB[1];
  float tAs = fmaf(xA, asv.x, yA * asv.y);
  float tAd = fmaf(xA, adv.x, yA * adv.y);
  float tBs = fmaf(xB, asv.x, yB * asv.y);
  float tBd = fmaf(xB, adv.x, yB * adv.y);
#pragma unroll
  for (int off = 1; off < 64; off <<= 1) {
    tAs += __shfl_xor(tAs, off);
    tAd += __shfl_xor(tAd, off);
    tBs += __shfl_xor(tBs, off);
    tBd += __shfl_xor(tBd, off);
  }
  const float adA = tAd, adB = tBd;
  float eA = tAs + adA, eB = tBs + adB;
  eA = (eA > 0.f) ? eA : kNegSlope * eA;
  eB = (eB > 0.f) ? eB : kNegSlope * eB;
  const float wsA = fexp(eA);
  const float wsB = fexp(eB);
  float dA = wsA, dB = wsB;
  float2 aA = make_float2(wsA * xA, wsA * yA);
  float2 aB = make_float2(wsB * xB, wsB * yB);
  const int cm = (c0 > c1) ? c0 : c1;
  int i = 1;
  for (; i + 2 <= cm; i += 2) {
    const int jA0 = (i < c0) ? i : 0, jA1 = (i + 1 < c0) ? i + 1 : 0;
    const int jB0 = (i < c1) ? i : 0, jB1 = (i + 1 < c1) ? i + 1 : 0;
    const int sA0 = csr_src[s0 + jA0];
    const int sA1 = csr_src[s0 + jA1];
    const int sB0 = csr_src[s1 + jB0];
    const int sB1 = csr_src[s1 + jB1];
    const half2v vA0 = *(const half2v*)(h + (size_t)sA0 * 128 + lane * 2);
    const half2v vA1 = *(const half2v*)(h + (size_t)sA1 * 128 + lane * 2);
    const half2v vB0 = *(const half2v*)(h + (size_t)sB0 * 128 + lane * 2);
    const half2v vB1 = *(const half2v*)(h + (size_t)sB1 * 128 + lane * 2);
    const float xA0 = (float)vA0[0], yA0 = (float)vA0[1];
    const float xA1 = (float)vA1[0], yA1 = (float)vA1[1];
    const float xB0 = (float)vB0[0], yB0 = (float)vB0[1];
    const float xB1 = (float)vB1[0], yB1 = (float)vB1[1];
    float tA0 = fmaf(xA0, asv.x, yA0 * asv.y);
    float tA1 = fmaf(xA1, asv.x, yA1 * asv.y);
    float tB0 = fmaf(xB0, asv.x, yB0 * asv.y);
    float tB1 = fmaf(xB1, asv.x, yB1 * asv.y);
#pragma unroll
    for (int off = 1; off < 64; off <<= 1) {
      tA0 += __shfl_xor(tA0, off);
      tA1 += __shfl_xor(tA1, off);
      tB0 += __shfl_xor(tB0, off);
      tB1 += __shfl_xor(tB1, off);
    }
    float eA0 = tA0 + adA, eA1 = tA1 + adA;
    float eB0 = tB0 + adB, eB1 = tB1 + adB;
    eA0 = (eA0 > 0.f) ? eA0 : kNegSlope * eA0;
    eA1 = (eA1 > 0.f) ? eA1 : kNegSlope * eA1;
    eB0 = (eB0 > 0.f) ? eB0 : kNegSlope * eB0;
    eB1 = (eB1 > 0.f) ? eB1 : kNegSlope * eB1;
    const float wA0 = (i < c0) ? fexp(eA0) : 0.f;
    const float wA1 = (i + 1 < c0) ? fexp(eA1) : 0.f;
    const float wB0 = (i < c1) ? fexp(eB0) : 0.f;
    const float wB1 = (i + 1 < c1) ? fexp(eB1) : 0.f;
    dA += wA0 + wA1;
    dB += wB0 + wB1;
    aA.x = fmaf(wA0, xA0, aA.x); aA.x = fmaf(wA1, xA1, aA.x);
    aA.y = fmaf(wA0, yA0, aA.y); aA.y = fmaf(wA1, yA1, aA.y);
    aB.x = fmaf(wB0, xB0, aB.x); aB.x = fmaf(wB1, xB1, aB.x);
    aB.y = fmaf(wB0, yB0, aB.y); aB.y = fmaf(wB1, yB1, aB.y);
  }
  if (i < cm) {
    const int jA = (i < c0) ? i : 0;
    const int jB = (i < c1) ? i : 0;
    const int sA = csr_src[s0 + jA];
    const int sB = csr_src[s1 + jB];
    const half2v vA = *(const half2v*)(h + (size_t)sA * 128 + lane * 2);
    const half2v vB = *(const half2v*)(h + (size_t)sB * 128 + lane * 2);
    const float xA2 = (float)vA[0], yA2 = (float)vA[1];
    const float xB2 = (float)vB[0], yB2 = (float)vB[1];
    float tA = fmaf(xA2, asv.x, yA2 * asv.y);
    float tB = fmaf(xB2, asv.x, yB2 * asv.y);
#pragma unroll
    for (int off = 1; off < 64; off <<= 1) {
      tA += __shfl_xor(tA, off);
      tB += __shfl_xor(tB, off);
    }
    float eA2 = tA + adA, eB2 = tB + adB;
    eA2 = (eA2 > 0.f) ? eA2 : kNegSlope * eA2;
    eB2 = (eB2 > 0.f) ? eB2 : kNegSlope * eB2;
    const float wA = (i < c0) ? fexp(eA2) : 0.f;
    const float wB = (i < c1) ? fexp(eB2) : 0.f;
    dA += wA;
    dB += wB;
    aA.x = fmaf(wA, xA2, aA.x);
    aA.y = fmaf(wA, yA2, aA.y);
    aB.x = fmaf(wB, xB2, aB.x);
    aB.y = fmaf(wB, yB2, aB.y);
  }
  const float invA = 1.f / (dA + 1e-16f);
  const float invB = 1.f / (dB + 1e-16f);
  *(float2*)(out + (size_t)n0 * 128 + lane * 2) =
      make_float2(aA.x * invA + bias[lane * 2],
                  aA.y * invA + bias[lane * 2 + 1]);
  if (has1)
    *(float2*)(out + (size_t)n1r * 128 + lane * 2) =
        make_float2(aB.x * invB + bias[lane * 2],
                    aB.y * invB + bias[lane * 2 + 1]);
}

// ------- global max pool over sorted batch (both encoders, 1 launch) ---
__global__ void pool_max2(const float* __restrict__ x, const int* __restrict__ bt1,
                          const int* __restrict__ bt2, float* __restrict__ emb) {
  __shared__ int lohi[2];
  const int enc = blockIdx.x >> 8;
  const int g = blockIdx.x & 255;
  const int* batch = enc ? bt2 : bt1;
  const float* xx = x + (size_t)enc * kN * 128;
  if (threadIdx.x == 0) {
    int lo = 0, hi = kN;
    while (lo < hi) {
      const int mid = (lo + hi) >> 1;
      if (batch[mid] < g) lo = mid + 1; else hi = mid;
    }
    lohi[0] = lo;
    hi = kN;
    while (lo < hi) {
      const int mid = (lo + hi) >> 1;
      if (batch[mid] < g + 1) lo = mid + 1; else hi = mid;
    }
    lohi[1] = lo;
  }
  __syncthreads();
  const int lo = lohi[0], hi = lohi[1];
  const int c = threadIdx.x;  // 128 channels
  float m = -1e30f;
  for (int nid = lo; nid < hi; ++nid) m = fmaxf(m, xx[(size_t)nid * 128 + c]);
  emb[(size_t)blockIdx.x * 128 + c] = (lo < hi) ? m : 0.f;
}
// ------- single-encoder pool (fallback path) --------------------------
__global__ void pool_max(const float* __restrict__ x, const int* __restrict__ batch,
                         float* __restrict__ emb, int n_nodes) {
  __shared__ int lohi[2];
  const int g = blockIdx.x;
  if (threadIdx.x == 0) {
    int lo = 0, hi = n_nodes;
    while (lo < hi) {
      const int mid = (lo + hi) >> 1;
      if (batch[mid] < g) lo = mid + 1; else hi = mid;
    }
    lohi[0] = lo;
    hi = n_nodes;
    while (lo < hi) {
      const int mid = (lo + hi) >> 1;
      if (batch[mid] < g + 1) lo = mid + 1; else hi = mid;
    }
    lohi[1] = lo;
  }
  __syncthreads();
  const int lo = lohi[0], hi = lohi[1];
  const int c = threadIdx.x;  // 128 channels
  float m = -1e30f;
  for (int nid = lo; nid < hi; ++nid) m = fmaxf(m, x[(size_t)nid * 128 + c]);
  emb[g * 128 + c] = (lo < hi) ? m : 0.f;
}

// ---------------- final MLP head --------------------------------------
__global__ void mlp_head(const float* __restrict__ e1, const float* __restrict__ e2,
                         const float* __restrict__ mw1, const float* __restrict__ mb1,
                         const float* __restrict__ mw2, const float* __restrict__ mb2,
                         float* __restrict__ out) {
  __shared__ float z[256];
  __shared__ float red[128];
  const int g = blockIdx.x;
  const int j = threadIdx.x;  // 128
  z[j] = e1[g * 128 + j];
  z[j + 128] = e2[g * 128 + j];
  __syncthreads();
  float acc = mb1[j];
  for (int k = 0; k < 256; ++k) acc = fmaf(z[k], mw1[k * 128 + j], acc);
  acc = fmaxf(acc, 0.f) * mw2[j];
  red[j] = acc;
  __syncthreads();
  for (int s = 64; s > 0; s >>= 1) {
    if (j < s) red[j] += red[j + s];
    __syncthreads();
  }
  if (j == 0) out[g] = red[0] + mb2[0];
}

// ---------------- launcher --------------------------------------------
namespace {
struct Bufs {
  _Float16 *R1h, *R2h;
  float *R1f, *R2f, *asrc, *adst;
  int *cnt, *start, *cursor, *csr, *total;
  _Float16 *Wth1, *Wth2, *Wth3;
  float* emb;
  size_t need;
};

Bufs plan(void* d_ws, int M, int E) {
  Bufs b;
  char* w = (char*)d_ws;
  size_t off = 0;
  auto take = [&](size_t bytes) -> void* {
    void* p = w + off;
    off += (bytes + 255) & ~(size_t)255;
    return p;
  };
  b.R1h = (_Float16*)take((size_t)M * 512 * 2);  // f16 activations
  b.R1f = (float*)b.R1h;                         // layer-3 out alias [M,128]
  b.R2h = (_Float16*)take((size_t)M * 512 * 2);  // h f16 (l3 h f16 [M,128])
  b.R2f = (float*)b.R2h;
  b.asrc = (float*)take((size_t)M * 4 * 4);      // (kept for ws layout stability)
  b.adst = (float*)take((size_t)M * 4 * 4);
  b.cnt = (int*)take((size_t)M * 4);
  b.start = (int*)take((size_t)M * 4);
  b.cursor = (int*)take((size_t)M * 4);
  b.csr = (int*)take((size_t)E * 4);
  b.total = (int*)take(256);
  b.Wth1 = (_Float16*)take((size_t)64 * 512 * 2);
  b.Wth2 = (_Float16*)take((size_t)512 * 512 * 2);
  b.Wth3 = (_Float16*)take((size_t)512 * 128 * 2);
  b.emb = (float*)take((size_t)2 * kG * 128 * 4);
  b.need = off;
  return b;
}

void run_layers(const Bufs& b, void* const* d_in, int M, hipStream_t stream) {
  const float* as1 = (const float*)d_in[7];
  const float* ad1 = (const float*)d_in[8];
  const float* b1 = (const float*)d_in[9];
  const float* as2 = (const float*)d_in[11];
  const float* ad2 = (const float*)d_in[12];
  const float* b2 = (const float*)d_in[13];
  const float* as3 = (const float*)d_in[15];
  const float* ad3 = (const float*)d_in[16];
  const float* b3 = (const float*)d_in[17];
  const int aggBlocks = (((M + 1) / 2) * 64 + 255) / 256;  // 2 nodes/wave
  const int RT128 = (M + 127) / 128;
  const int SP128 = (RT128 + 7) / 8;      // 128-row tile groups (XCD map)
  const int RT256 = (M + 255) / 256;
  const int SP256 = (RT256 + 7) / 8;      // 256-row tile groups

  // layer 1: [M,64] @ [64,512], BM=128, RING=3 (K=64: small tile — R9)
  gemm_ring<1, 128, 256, 2, 3><<<SP128 * 16, 256, 0, stream>>>(
      b.R1h, b.Wth1, b.R2h, M, 512, 64);
  gat_agg4<<<aggBlocks, 256, 0, stream>>>(b.R2h, as1, ad1, b.start, b.cnt,
                                          b.csr, b1, b.R1h, M);
  // layer 2: [M,512] @ [512,512], BM=256, RING=2 (64KB -> 2 blocks/CU)
  gemm_ring<1, 256, 256, 2, 2><<<SP256 * 16, 512, 0, stream>>>(
      b.R1h, b.Wth2, b.R2h, M, 512, 512);
  gat_agg4<<<aggBlocks, 256, 0, stream>>>(b.R2h, as2, ad2, b.start, b.cnt,
                                          b.csr, b2, b.R1h, M);
  // layer 3: [M,512] @ [512,128], BM=128, RING=3, h -> f16
  gemm_ring<1, 128, 128, 1, 3><<<SP128 * 8, 256, 0, stream>>>(
      b.R1h, b.Wth3, b.R2h, M, 128, 512);
  gat_agg_l3<<<aggBlocks, 256, 0, stream>>>(b.R2h, as3, ad3, b.start, b.cnt,
                                            b.csr, b3, b.R1f, M);
}
}  // namespace

extern "C" void kernel_launch(void* const* d_in, const int* in_sizes, int n_in,
                              void* d_out, int out_size, void* d_ws, size_t ws_size,
                              hipStream_t stream) {
  (void)in_sizes; (void)n_in; (void)out_size;
  const float* W1 = (const float*)d_in[6];
  const float* W2 = (const float*)d_in[10];
  const float* W3 = (const float*)d_in[14];
  const float* mw1 = (const float*)d_in[18];
  const float* mb1 = (const float*)d_in[19];
  const float* mw2 = (const float*)d_in[20];
  const float* mb2 = (const float*)d_in[21];

  // Prefer combined (both encoders batched, M=2N) if it fits the workspace.
  Bufs bc = plan(d_ws, 2 * kN, 2 * kE2);
  const bool combined = bc.need <= ws_size;
  Bufs b = combined ? bc : plan(d_ws, kN, kE2);

  const int wtot = 64 * 512 + 512 * 512 + 512 * 128;
  if (combined) {
    const int M = 2 * kN;
    const int* ei0 = (const int*)d_in[1];
    const int* ei1 = (const int*)d_in[4];
    prep_all<<<(M * 64 + wtot + 255) / 256, 256, 0, stream>>>(
        (const float*)d_in[0], (const float*)d_in[3], b.R1h, b.cnt, b.total,
        W1, b.Wth1, W2, b.Wth2, W3, b.Wth3);
    count_edges2<<<(2 * kE + 255) / 256, 256, 0, stream>>>(ei0 + kE, ei1 + kE,
                                                           b.cnt);
    alloc_ranges<<<(M + 255) / 256, 256, 0, stream>>>(b.cnt, b.start, b.cursor,
                                                      b.total, b.csr, M);
    fill_edges2<<<(2 * kE + 255) / 256, 256, 0, stream>>>(ei0, ei0 + kE, ei1,
                                                          ei1 + kE, b.cursor, b.csr);
    run_layers(b, d_in, M, stream);
    pool_max2<<<2 * kG, 128, 0, stream>>>(b.R1f, (const int*)d_in[2],
                                          (const int*)d_in[5], b.emb);
  } else {
    wt_split_all<<<(wtot + 255) / 256, 256, 0, stream>>>(W1, b.Wth1, W2, b.Wth2,
                                                         W3, b.Wth3);
    for (int enc = 0; enc < 2; ++enc) {
      const float* x = (const float*)d_in[enc * 3 + 0];
      const int* ei = (const int*)d_in[enc * 3 + 1];
      const int* batch = (const int*)d_in[enc * 3 + 2];
      prep<<<(kN * 64 + 255) / 256, 256, 0, stream>>>(x, b.R1h, b.cnt, b.total,
                                                      kN * 64, kN);
      count_edges<<<(kE + 255) / 256, 256, 0, stream>>>(ei + kE, b.cnt, kE);
      alloc_ranges<<<(kN + 255) / 256, 256, 0, stream>>>(b.cnt, b.start, b.cursor,
                                                         b.total, b.csr, kN);
      fill_edges<<<(kE + 255) / 256, 256, 0, stream>>>(ei, ei + kE, b.cursor, b.csr,
                                                       kE);
      run_layers(b, d_in, kN, stream);
      pool_max<<<kG, 128, 0, stream>>>(b.R1f, batch, b.emb + (size_t)enc * kG * 128,
                                       kN);
    }
  }
  mlp_head<<<kG, 128, 0, stream>>>(b.emb, b.emb + (size_t)kG * 128, mw1, mb1, mw2,
                                   mb2, (float*)d_out);
}

// Round 13
// 618.798 us; speedup vs baseline: 1.4382x; 1.0049x over previous
//
#include <hip/hip_runtime.h>
#include <cstdint>

namespace {
constexpr int kN = 50000;          // nodes per encoder
constexpr int kE = 200000;         // directed edges per encoder (pre self-loop)
constexpr int kE2 = kE + kN;       // with self loops (per encoder)
constexpr int kG = 256;            // graphs per encoder
constexpr float kNegSlope = 0.2f;
}

using half8   = __attribute__((ext_vector_type(8))) _Float16;
using half2v  = __attribute__((ext_vector_type(2))) _Float16;
using floatx4 = __attribute__((ext_vector_type(4))) float;

__device__ __forceinline__ void gld_lds16(const void* g, void* l) {
  __builtin_amdgcn_global_load_lds(
      (const __attribute__((address_space(1))) unsigned int*)g,
      (__attribute__((address_space(3))) unsigned int*)l, 16, 0, 0);
}

// fast exp: e^x = 2^(x*log2(e)) via hardware v_exp_f32 (no libm call)
__device__ __forceinline__ float fexp(float x) {
  return __builtin_amdgcn_exp2f(x * 1.44269504088896f);
}

// packed f16 dot: v_dot2_f32_f16 if available, else v_fma_mix fallback.
#if __has_builtin(__builtin_amdgcn_fdot2)
__device__ __forceinline__ float dot8h(const half8& v, const half2v* a) {
  const half2v* p = (const half2v*)&v;
  float t = __builtin_amdgcn_fdot2(p[0], a[0], 0.f, false);
  t = __builtin_amdgcn_fdot2(p[1], a[1], t, false);
  t = __builtin_amdgcn_fdot2(p[2], a[2], t, false);
  t = __builtin_amdgcn_fdot2(p[3], a[3], t, false);
  return t;
}
__device__ __forceinline__ float dot2h(const half2v v, const half2v a) {
  return __builtin_amdgcn_fdot2(v, a, 0.f, false);
}
#else
__device__ __forceinline__ float dot8h(const half8& v, const half2v* a) {
  float t = 0.f;
#pragma unroll
  for (int q = 0; q < 4; ++q) {
    t = fmaf((float)v[2 * q], (float)a[q][0], t);
    t = fmaf((float)v[2 * q + 1], (float)a[q][1], t);
  }
  return t;
}
__device__ __forceinline__ float dot2h(const half2v v, const half2v a) {
  return fmaf((float)v[0], (float)a[0], (float)v[1] * (float)a[1]);
}
#endif

// ---------------- fp16 MFMA GEMM: C[M,N] = A[M,K] @ B[K,N] -----------
// Per-layer best configs (R8/R9/R12 A/B):
//   l2: BM=256/BN=256, RING=2 (64KB -> 2 blocks/CU; R12 took it out of
//       the top-5 — staging-path occupancy was the limiter at 1 blk/CU)
//   l1/l3: BM=128, RING=3 dist-2 (R9 win)
// RING>=3: counted vmcnt, ONE barrier/tile, stage kt+DIST into freed slot.
// RING==2: two barriers/tile (dist-1 needs the end barrier), counted
// vmcnt(LPT) keeps next tile's loads in flight across both.
template <int OUTF16, int BM, int BN, int CT, int RING>
__global__ __launch_bounds__((BM == 256) ? 512 : 256, 2) void gemm_ring(
    const _Float16* __restrict__ A, const _Float16* __restrict__ B,
    void* __restrict__ Cv, int M, int N, int K) {
  constexpr int THREADS = (BM == 256) ? 512 : 256;
  constexpr int ASL = BM * 4;              // A slots/tile (16B each)
  constexpr int BSL = BN * 4;              // B slots/tile
  constexpr int SLOT = (ASL + BSL) * 16;
  constexpr int LPT = (ASL + BSL) / THREADS;
  constexpr int DIST = RING - 1;
  constexpr int WAITN = (RING == 2) ? LPT : (DIST - 1) * LPT;
  constexpr int WAVES = THREADS / 64;
  constexpr int WN = (BM == 256) ? 4 : 2;
  constexpr int WM = WAVES / WN;           // 2
  constexpr int WTM = BM / WM;             // 128 or 64
  constexpr int WTN = BN / WN;             // 64 or 128
  constexpr int MI = WTM / 16;
  constexpr int NI = WTN / 16;
  __shared__ alignas(16) char smem[RING * SLOT];
  const int t = threadIdx.x;
  const int w = t >> 6, l = t & 63;
  const int x = blockIdx.x & 7, s = blockIdx.x >> 3;
  const int col = (CT == 1) ? 0 : (s & (CT - 1));
  const int rt = ((CT == 1) ? s : (s >> 1)) * 8 + x;
  const int bm = rt * BM;
  const int bn = col * BN;
  if (bm >= M) return;  // padded row-tiles: whole block exits (no barrier)
  const int wr = w / WN, wc = w % WN;
  const int quad = l >> 4, lrow = l & 15;

  floatx4 acc[MI][NI];
#pragma unroll
  for (int mi = 0; mi < MI; ++mi)
#pragma unroll
    for (int ni = 0; ni < NI; ++ni) acc[mi][ni] = (floatx4){0.f, 0.f, 0.f, 0.f};

  // stage tile kt's A-part / B-part into the given ring slot
  auto stageA = [&](int slot, int kt) {
    char* buf = smem + (size_t)slot * SLOT;
    int k0 = kt * 32;
    k0 = (k0 > K - 32) ? (K - 32) : k0;  // clamp: beyond-NT garbage stays in-bounds
#pragma unroll
    for (int i = 0; i < ASL / THREADS; ++i) {
      const int sl = i * THREADS + t;
      const int row = ((sl >> 6) << 4) + (sl & 15);
      const int q = (sl >> 4) & 3;
      int ga = bm + row;
      ga = (ga < M) ? ga : (M - 1);      // clamp: keep lanes active
      gld_lds16(A + (size_t)ga * K + k0 + q * 8, buf + sl * 16);
    }
  };
  auto stageB = [&](int slot, int kt) {
    char* buf = smem + (size_t)slot * SLOT + ASL * 16;
    int k0 = kt * 32;
    k0 = (k0 > K - 32) ? (K - 32) : k0;
#pragma unroll
    for (int i = 0; i < BSL / THREADS; ++i) {
      const int sl = i * THREADS + t;
      const int row = ((sl >> 6) << 4) + (sl & 15);
      const int q = (sl >> 4) & 3;
      gld_lds16(B + (size_t)(bn + row) * K + k0 + q * 8, buf + sl * 16);
    }
  };

  // prologue: tiles 0..DIST-1 in flight
#pragma unroll
  for (int p = 0; p < DIST; ++p) {
    stageA(p, p);
    stageB(p, p);
  }

  const int NT = K >> 5;
  int cur = 0;
  for (int kt = 0; kt < NT; ++kt) {
    char* bufc = smem + (size_t)cur * SLOT;
    if constexpr (RING == 2) {
      stageA(cur ^ 1, kt + 1);
      stageB(cur ^ 1, kt + 1);
      asm volatile("s_waitcnt vmcnt(4)" ::: "memory");  // kt's LPT landed
      __builtin_amdgcn_s_barrier();
      asm volatile("" ::: "memory");
      half8 fa[MI], fb[NI];
#pragma unroll
      for (int ni = 0; ni < NI; ++ni)
        fb[ni] = *(const half8*)(bufc + ASL * 16 + ((wc * NI + ni) << 10) + l * 16);
#pragma unroll
      for (int mi = 0; mi < MI; ++mi)
        fa[mi] = *(const half8*)(bufc + ((wr * MI + mi) << 10) + l * 16);
      __builtin_amdgcn_s_setprio(1);
#pragma unroll
      for (int mi = 0; mi < MI; ++mi)
#pragma unroll
        for (int ni = 0; ni < NI; ++ni)
          acc[mi][ni] = __builtin_amdgcn_mfma_f32_16x16x32_f16(
              fa[mi], fb[ni], acc[mi][ni], 0, 0, 0);
      __builtin_amdgcn_s_setprio(0);
      asm volatile("" ::: "memory");
      __builtin_amdgcn_s_barrier();  // slot[cur] free for re-staging
      cur ^= 1;
    } else {
      const int stg = (cur == 0) ? (RING - 1) : (cur - 1);
      if constexpr (WAITN == 8)
        asm volatile("s_waitcnt vmcnt(8)" ::: "memory");
      else if constexpr (WAITN == 6)
        asm volatile("s_waitcnt vmcnt(6)" ::: "memory");
      else
        asm volatile("s_waitcnt vmcnt(4)" ::: "memory");
      __builtin_amdgcn_s_barrier();  // slot[cur] ready AND slot[stg] consumed
      asm volatile("" ::: "memory");
      stageA(stg, kt + DIST);        // -> slot of tile kt-1, safe after barrier
      half8 fa[MI], fb[NI];
#pragma unroll
      for (int ni = 0; ni < NI; ++ni)
        fb[ni] = *(const half8*)(bufc + ASL * 16 + ((wc * NI + ni) << 10) + l * 16);
#pragma unroll
      for (int mi = 0; mi < MI / 2; ++mi)
        fa[mi] = *(const half8*)(bufc + ((wr * MI + mi) << 10) + l * 16);
      __builtin_amdgcn_s_setprio(1);
#pragma unroll
      for (int mi = 0; mi < MI / 2; ++mi)
#pragma unroll
        for (int ni = 0; ni < NI; ++ni)
          acc[mi][ni] = __builtin_amdgcn_mfma_f32_16x16x32_f16(
              fa[mi], fb[ni], acc[mi][ni], 0, 0, 0);
      __builtin_amdgcn_s_setprio(0);
      stageB(stg, kt + DIST);        // remaining loads of tile kt+DIST
#pragma unroll
      for (int mi = MI / 2; mi < MI; ++mi)
        fa[mi] = *(const half8*)(bufc + ((wr * MI + mi) << 10) + l * 16);
      __builtin_amdgcn_s_setprio(1);
#pragma unroll
      for (int mi = MI / 2; mi < MI; ++mi)
#pragma unroll
        for (int ni = 0; ni < NI; ++ni)
          acc[mi][ni] = __builtin_amdgcn_mfma_f32_16x16x32_f16(
              fa[mi], fb[ni], acc[mi][ni], 0, 0, 0);
      __builtin_amdgcn_s_setprio(0);
      cur = (cur == RING - 1) ? 0 : (cur + 1);
      // no end-of-tile barrier: distance-DIST ring tolerates the drift
    }
  }
  asm volatile("s_waitcnt vmcnt(0)" ::: "memory");  // drain garbage prefetches
  // epilogue: C/D layout col=lane&15, row=quad*4+reg
  const int colbase = bn + wc * WTN + lrow;
#pragma unroll
  for (int mi = 0; mi < MI; ++mi) {
    const int rbase = bm + wr * WTM + mi * 16 + quad * 4;
#pragma unroll
    for (int r = 0; r < 4; ++r) {
      const int grow = rbase + r;
      if (grow < M) {
        if constexpr (OUTF16) {
          _Float16* C = (_Float16*)Cv;
#pragma unroll
          for (int ni = 0; ni < NI; ++ni)
            C[(size_t)grow * N + colbase + ni * 16] = (_Float16)acc[mi][ni][r];
        } else {
          float* C = (float*)Cv;
#pragma unroll
          for (int ni = 0; ni < NI; ++ni)
            C[(size_t)grow * N + colbase + ni * 16] = acc[mi][ni][r];
        }
      }
    }
  }
}

// ------- all three weight transposes + f16 casts (fallback path) ------
__global__ void wt_split_all(const float* __restrict__ W1, _Float16* Th1,
                             const float* __restrict__ W2, _Float16* Th2,
                             const float* __restrict__ W3, _Float16* Th3) {
  int idx = blockIdx.x * blockDim.x + threadIdx.x;
  const float* W;
  _Float16* Th;
  int K, N;
  if (idx < 64 * 512) {
    W = W1; Th = Th1; K = 64; N = 512;
  } else if (idx < 64 * 512 + 512 * 512) {
    idx -= 64 * 512;
    W = W2; Th = Th2; K = 512; N = 512;
  } else if (idx < 64 * 512 + 512 * 512 + 512 * 128) {
    idx -= 64 * 512 + 512 * 512;
    W = W3; Th = Th3; K = 512; N = 128;
  } else {
    return;
  }
  const int k = idx / N;
  const int n = idx - k * N;
  Th[n * K + k] = (_Float16)W[idx];
}

// --- combined prep: x casts + cnt=1 + total=0 + weight transposes -----
__global__ void prep_all(const float* __restrict__ x0, const float* __restrict__ x1,
                         _Float16* __restrict__ Xh, int* __restrict__ cnt,
                         int* __restrict__ total,
                         const float* __restrict__ W1, _Float16* Th1,
                         const float* __restrict__ W2, _Float16* Th2,
                         const float* __restrict__ W3, _Float16* Th3) {
  const int idx = blockIdx.x * blockDim.x + threadIdx.x;
  const int half = kN * 64;
  if (idx < half) {
    Xh[idx] = (_Float16)x0[idx];
  } else if (idx < 2 * half) {
    Xh[idx] = (_Float16)x1[idx - half];
  } else {
    int e = idx - 2 * half;
    const float* W;
    _Float16* Th;
    int K, N;
    if (e < 64 * 512) {
      W = W1; Th = Th1; K = 64; N = 512;
    } else if (e < 64 * 512 + 512 * 512) {
      e -= 64 * 512;
      W = W2; Th = Th2; K = 512; N = 512;
    } else if (e < 64 * 512 + 512 * 512 + 512 * 128) {
      e -= 64 * 512 + 512 * 512;
      W = W3; Th = Th3; K = 512; N = 128;
    } else {
      W = nullptr; Th = nullptr; K = N = 0;
    }
    if (W) {
      const int k = e / N;
      const int n = e - k * N;
      Th[n * K + k] = (_Float16)W[e];
    }
  }
  if (idx < 2 * kN) cnt[idx] = 1;  // the self loop
  if (idx == 0) *total = 0;
}
// ------- single-encoder prep (fallback path) --------------------------
__global__ void prep(const float* __restrict__ X, _Float16* __restrict__ Xh,
                     int* __restrict__ cnt, int* __restrict__ total, int nsplit,
                     int n) {
  const int idx = blockIdx.x * blockDim.x + threadIdx.x;
  if (idx < nsplit) Xh[idx] = (_Float16)X[idx];
  if (idx < n) cnt[idx] = 1;
  if (idx == 0) *total = 0;
}

// ---------------- CSR (by dst) build ----------------------------------
__global__ void count_edges2(const int* __restrict__ d0, const int* __restrict__ d1,
                             int* __restrict__ cnt) {
  const int i = blockIdx.x * blockDim.x + threadIdx.x;
  if (i < kE) atomicAdd(&cnt[d0[i]], 1);
  else if (i < 2 * kE) atomicAdd(&cnt[d1[i - kE] + kN], 1);
}
__global__ void fill_edges2(const int* __restrict__ s0, const int* __restrict__ d0,
                            const int* __restrict__ s1, const int* __restrict__ d1,
                            int* __restrict__ cursor, int* __restrict__ csr) {
  const int i = blockIdx.x * blockDim.x + threadIdx.x;
  if (i < kE) {
    const int p = atomicAdd(&cursor[d0[i]], 1);
    csr[p] = s0[i];
  } else if (i < 2 * kE) {
    const int j = i - kE;
    const int p = atomicAdd(&cursor[d1[j] + kN], 1);
    csr[p] = s1[j] + kN;
  }
}
__global__ void count_edges(const int* __restrict__ dst, int* __restrict__ cnt,
                            int ne) {
  const int i = blockIdx.x * blockDim.x + threadIdx.x;
  if (i < ne) atomicAdd(&cnt[dst[i]], 1);
}
__global__ void fill_edges(const int* __restrict__ src, const int* __restrict__ dst,
                           int* __restrict__ cursor, int* __restrict__ csr, int ne) {
  const int i = blockIdx.x * blockDim.x + threadIdx.x;
  if (i < ne) {
    const int p = atomicAdd(&cursor[dst[i]], 1);
    csr[p] = src[i];
  }
}
__global__ void alloc_ranges(const int* __restrict__ cnt, int* __restrict__ start,
                             int* __restrict__ cursor, int* __restrict__ total,
                             int* __restrict__ csr, int n) {
  const int i = blockIdx.x * blockDim.x + threadIdx.x;
  const int lane = threadIdx.x & 63;
  const int v = (i < n) ? cnt[i] : 0;
  int sc = v;
#pragma unroll
  for (int off = 1; off < 64; off <<= 1) {
    const int t = __shfl_up(sc, off);
    if (lane >= off) sc += t;
  }
  const int wtot = __shfl(sc, 63);
  int base = 0;
  if (lane == 63) base = atomicAdd(total, wtot);
  base = __shfl(base, 63);
  const int st = base + sc - v;
  if (i < n) {
    start[i] = st;
    cursor[i] = st + 1;
    csr[st] = i;  // self loop first
  }
}

// ---------------- GAT aggregate, layers 1-2 (f16 h) -------------------
// R19 2-node interleave (per-NODE dependent chain doubled in flight) +
// R25: packed-f16 dots. agg was VALU-issue-bound (64% VALUBusy); the
// per-edge dot (8 cvt + 8 fma) becomes 4 v_dot2_f32_f16 on pre-cast
// half2 a-vectors; the accumulate uses inline (float) casts so the
// compiler emits v_fma_mix (no cvt materialization). ~30 -> ~17 ops/edge.
__global__ void gat_agg4(const _Float16* __restrict__ h,
                         const float* __restrict__ a_src,
                         const float* __restrict__ a_dst,
                         const int* __restrict__ start, const int* __restrict__ cnt,
                         const int* __restrict__ csr_src,
                         const float* __restrict__ bias,
                         _Float16* __restrict__ outH, int n_nodes) {
  const int gtid = blockIdx.x * blockDim.x + threadIdx.x;
  const int wid = gtid >> 6;
  const int lane = threadIdx.x & 63;
  const int n0 = wid * 2;
  if (n0 >= n_nodes) return;
  const int n1r = (n0 + 1 < n_nodes) ? (n0 + 1) : n0;
  const bool has1 = (n0 + 1 < n_nodes);
  const int ch = lane * 8;
  half2v asH[4], adH[4];
#pragma unroll
  for (int q = 0; q < 4; ++q) {
    asH[q][0] = (_Float16)a_src[ch + 2 * q];
    asH[q][1] = (_Float16)a_src[ch + 2 * q + 1];
    adH[q][0] = (_Float16)a_dst[ch + 2 * q];
    adH[q][1] = (_Float16)a_dst[ch + 2 * q + 1];
  }
  const int s0 = start[n0], c0 = cnt[n0];
  const int s1 = start[n1r];
  const int c1 = has1 ? cnt[n1r] : 0;
  // self gathers for both nodes (csr[s]==node; gives dst-dot + self edge)
  const half8 vsA = *(const half8*)(h + (size_t)n0 * 512 + ch);
  const half8 vsB = *(const half8*)(h + (size_t)n1r * 512 + ch);
  float tAs = dot8h(vsA, asH), tAd = dot8h(vsA, adH);
  float tBs = dot8h(vsB, asH), tBd = dot8h(vsB, adH);
#pragma unroll
  for (int off = 1; off < 16; off <<= 1) {
    tAs += __shfl_xor(tAs, off);
    tAd += __shfl_xor(tAd, off);
    tBs += __shfl_xor(tBs, off);
    tBd += __shfl_xor(tBd, off);
  }
  const float adA = tAd, adB = tBd;
  float eA = tAs + adA, eB = tBs + adB;
  eA = (eA > 0.f) ? eA : kNegSlope * eA;
  eB = (eB > 0.f) ? eB : kNegSlope * eB;
  const float wsA = fexp(eA);
  const float wsB = fexp(eB);
  float dA = wsA, dB = wsB;
  float aA[8], aB[8];
#pragma unroll
  for (int j = 0; j < 8; ++j) {
    aA[j] = wsA * (float)vsA[j];
    aB[j] = wsB * (float)vsB[j];
  }
  const int cm = (c0 > c1) ? c0 : c1;
  int i = 1;
  for (; i + 2 <= cm; i += 2) {
    const int jA0 = (i < c0) ? i : 0, jA1 = (i + 1 < c0) ? i + 1 : 0;
    const int jB0 = (i < c1) ? i : 0, jB1 = (i + 1 < c1) ? i + 1 : 0;
    const int sA0 = csr_src[s0 + jA0];
    const int sA1 = csr_src[s0 + jA1];
    const int sB0 = csr_src[s1 + jB0];
    const int sB1 = csr_src[s1 + jB1];
    const half8 vA0 = *(const half8*)(h + (size_t)sA0 * 512 + ch);
    const half8 vA1 = *(const half8*)(h + (size_t)sA1 * 512 + ch);
    const half8 vB0 = *(const half8*)(h + (size_t)sB0 * 512 + ch);
    const half8 vB1 = *(const half8*)(h + (size_t)sB1 * 512 + ch);
    float tA0 = dot8h(vA0, asH);
    float tA1 = dot8h(vA1, asH);
    float tB0 = dot8h(vB0, asH);
    float tB1 = dot8h(vB1, asH);
#pragma unroll
    for (int off = 1; off < 16; off <<= 1) {
      tA0 += __shfl_xor(tA0, off);
      tA1 += __shfl_xor(tA1, off);
      tB0 += __shfl_xor(tB0, off);
      tB1 += __shfl_xor(tB1, off);
    }
    float eA0 = tA0 + adA, eA1 = tA1 + adA;
    float eB0 = tB0 + adB, eB1 = tB1 + adB;
    eA0 = (eA0 > 0.f) ? eA0 : kNegSlope * eA0;
    eA1 = (eA1 > 0.f) ? eA1 : kNegSlope * eA1;
    eB0 = (eB0 > 0.f) ? eB0 : kNegSlope * eB0;
    eB1 = (eB1 > 0.f) ? eB1 : kNegSlope * eB1;
    const float wA0 = (i < c0) ? fexp(eA0) : 0.f;
    const float wA1 = (i + 1 < c0) ? fexp(eA1) : 0.f;
    const float wB0 = (i < c1) ? fexp(eB0) : 0.f;
    const float wB1 = (i + 1 < c1) ? fexp(eB1) : 0.f;
    dA += wA0 + wA1;
    dB += wB0 + wB1;
#pragma unroll
    for (int j = 0; j < 8; ++j) {
      aA[j] = fmaf(wA0, (float)vA0[j], aA[j]);
      aA[j] = fmaf(wA1, (float)vA1[j], aA[j]);
      aB[j] = fmaf(wB0, (float)vB0[j], aB[j]);
      aB[j] = fmaf(wB1, (float)vB1[j], aB[j]);
    }
  }
  if (i < cm) {  // tail: at most one edge per node
    const int jA = (i < c0) ? i : 0;
    const int jB = (i < c1) ? i : 0;
    const int sA = csr_src[s0 + jA];
    const int sB = csr_src[s1 + jB];
    const half8 vA = *(const half8*)(h + (size_t)sA * 512 + ch);
    const half8 vB = *(const half8*)(h + (size_t)sB * 512 + ch);
    float tA = dot8h(vA, asH);
    float tB = dot8h(vB, asH);
#pragma unroll
    for (int off = 1; off < 16; off <<= 1) {
      tA += __shfl_xor(tA, off);
      tB += __shfl_xor(tB, off);
    }
    float eA2 = tA + adA, eB2 = tB + adB;
    eA2 = (eA2 > 0.f) ? eA2 : kNegSlope * eA2;
    eB2 = (eB2 > 0.f) ? eB2 : kNegSlope * eB2;
    const float wA = (i < c0) ? fexp(eA2) : 0.f;
    const float wB = (i < c1) ? fexp(eB2) : 0.f;
    dA += wA;
    dB += wB;
#pragma unroll
    for (int j = 0; j < 8; ++j) {
      aA[j] = fmaf(wA, (float)vA[j], aA[j]);
      aB[j] = fmaf(wB, (float)vB[j], aB[j]);
    }
  }
  const float invA = 1.f / (dA + 1e-16f);
  const float invB = 1.f / (dB + 1e-16f);
  half8 HA, HB;
#pragma unroll
  for (int j = 0; j < 8; ++j) {
    float vA = aA[j] * invA + bias[ch + j];
    vA = (vA > 0.f) ? vA : (fexp(vA) - 1.f);  // elu via hw exp
    HA[j] = (_Float16)vA;
    float vB = aB[j] * invB + bias[ch + j];
    vB = (vB > 0.f) ? vB : (fexp(vB) - 1.f);
    HB[j] = (_Float16)vB;
  }
  *(half8*)(outH + (size_t)n0 * 512 + ch) = HA;
  if (has1) *(half8*)(outH + (size_t)n1r * 512 + ch) = HB;
}

// ---------- GAT aggregate, layer 3 (H=1, f16 h, 2 nodes/wave) ---------
__global__ void gat_agg_l3(const _Float16* __restrict__ h,
                           const float* __restrict__ a_src,
                           const float* __restrict__ a_dst,
                           const int* __restrict__ start, const int* __restrict__ cnt,
                           const int* __restrict__ csr_src,
                           const float* __restrict__ bias,
                           float* __restrict__ out, int n_nodes) {
  const int gtid = blockIdx.x * blockDim.x + threadIdx.x;
  const int wid = gtid >> 6;
  const int lane = threadIdx.x & 63;
  const int n0 = wid * 2;
  if (n0 >= n_nodes) return;
  const int n1r = (n0 + 1 < n_nodes) ? (n0 + 1) : n0;
  const bool has1 = (n0 + 1 < n_nodes);
  half2v asH, adH;
  asH[0] = (_Float16)a_src[lane * 2];
  asH[1] = (_Float16)a_src[lane * 2 + 1];
  adH[0] = (_Float16)a_dst[lane * 2];
  adH[1] = (_Float16)a_dst[lane * 2 + 1];
  const int s0 = start[n0], c0 = cnt[n0];
  const int s1 = start[n1r];
  const int c1 = has1 ? cnt[n1r] : 0;
  // self gathers
  const half2v vsA = *(const half2v*)(h + (size_t)n0 * 128 + lane * 2);
  const half2v vsB = *(const half2v*)(h + (size_t)n1r * 128 + lane * 2);
  float tAs = dot2h(vsA, asH), tAd = dot2h(vsA, adH);
  float tBs = dot2h(vsB, asH), tBd = dot2h(vsB, adH);
#pragma unroll
  for (int off = 1; off < 64; off <<= 1) {
    tAs += __shfl_xor(tAs, off);
    tAd += __shfl_xor(tAd, off);
    tBs += __shfl_xor(tBs, off);
    tBd += __shfl_xor(tBd, off);
  }
  const float adA = tAd, adB = tBd;
  float eA = tAs + adA, eB = tBs + adB;
  eA = (eA > 0.f) ? eA : kNegSlope * eA;
  eB = (eB > 0.f) ? eB : kNegSlope * eB;
  const float wsA = fexp(eA);
  const float wsB = fexp(eB);
  float dA = wsA, dB = wsB;
  float2 aA = make_float2(wsA * (float)vsA[0], wsA * (float)vsA[1]);
  float2 aB = make_float2(wsB * (float)vsB[0], wsB * (float)vsB[1]);
  const int cm = (c0 > c1) ? c0 : c1;
  int i = 1;
  for (; i + 2 <= cm; i += 2) {
    const int jA0 = (i < c0) ? i : 0, jA1 = (i + 1 < c0) ? i + 1 : 0;
    const int jB0 = (i < c1) ? i : 0, jB1 = (i + 1 < c1) ? i + 1 : 0;
    const int sA0 = csr_src[s0 + jA0];
    const int sA1 = csr_src[s0 + jA1];
    const int sB0 = csr_src[s1 + jB0];
    const int sB1 = csr_src[s1 + jB1];
    const half2v vA0 = *(const half2v*)(h + (size_t)sA0 * 128 + lane * 2);
    const half2v vA1 = *(const half2v*)(h + (size_t)sA1 * 128 + lane * 2);
    const half2v vB0 = *(const half2v*)(h + (size_t)sB0 * 128 + lane * 2);
    const half2v vB1 = *(const half2v*)(h + (size_t)sB1 * 128 + lane * 2);
    float tA0 = dot2h(vA0, asH);
    float tA1 = dot2h(vA1, asH);
    float tB0 = dot2h(vB0, asH);
    float tB1 = dot2h(vB1, asH);
#pragma unroll
    for (int off = 1; off < 64; off <<= 1) {
      tA0 += __shfl_xor(tA0, off);
      tA1 += __shfl_xor(tA1, off);
      tB0 += __shfl_xor(tB0, off);
      tB1 += __shfl_xor(tB1, off);
    }
    float eA0 = tA0 + adA, eA1 = tA1 + adA;
    float eB0 = tB0 + adB, eB1 = tB1 + adB;
    eA0 = (eA0 > 0.f) ? eA0 : kNegSlope * eA0;
    eA1 = (eA1 > 0.f) ? eA1 : kNegSlope * eA1;
    eB0 = (eB0 > 0.f) ? eB0 : kNegSlope * eB0;
    eB1 = (eB1 > 0.f) ? eB1 : kNegSlope * eB1;
    const float wA0 = (i < c0) ? fexp(eA0) : 0.f;
    const float wA1 = (i + 1 < c0) ? fexp(eA1) : 0.f;
    const float wB0 = (i < c1) ? fexp(eB0) : 0.f;
    const float wB1 = (i + 1 < c1) ? fexp(eB1) : 0.f;
    dA += wA0 + wA1;
    dB += wB0 + wB1;
    aA.x = fmaf(wA0, (float)vA0[0], aA.x); aA.x = fmaf(wA1, (float)vA1[0], aA.x);
    aA.y = fmaf(wA0, (float)vA0[1], aA.y); aA.y = fmaf(wA1, (float)vA1[1], aA.y);
    aB.x = fmaf(wB0, (float)vB0[0], aB.x); aB.x = fmaf(wB1, (float)vB1[0], aB.x);
    aB.y = fmaf(wB0, (float)vB0[1], aB.y); aB.y = fmaf(wB1, (float)vB1[1], aB.y);
  }
  if (i < cm) {
    const int jA = (i < c0) ? i : 0;
    const int jB = (i < c1) ? i : 0;
    const int sA = csr_src[s0 + jA];
    const int sB = csr_src[s1 + jB];
    const half2v vA = *(const half2v*)(h + (size_t)sA * 128 + lane * 2);
    const half2v vB = *(const half2v*)(h + (size_t)sB * 128 + lane * 2);
    float tA = dot2h(vA, asH);
    float tB = dot2h(vB, asH);
#pragma unroll
    for (int off = 1; off < 64; off <<= 1) {
      tA += __shfl_xor(tA, off);
      tB += __shfl_xor(tB, off);
    }
    float eA2 = tA + adA, eB2 = tB + adB;
    eA2 = (eA2 > 0.f) ? eA2 : kNegSlope * eA2;
    eB2 = (eB2 > 0.f) ? eB2 : kNegSlope * eB2;
    const float wA = (i < c0) ? fexp(eA2) : 0.f;
    const float wB = (i < c1) ? fexp(eB2) : 0.f;
    dA += wA;
    dB += wB;
    aA.x = fmaf(wA, (float)vA[0], aA.x);
    aA.y = fmaf(wA, (float)vA[1], aA.y);
    aB.x = fmaf(wB, (float)vB[0], aB.x);
    aB.y = fmaf(wB, (float)vB[1], aB.y);
  }
  const float invA = 1.f / (dA + 1e-16f);
  const float invB = 1.f / (dB + 1e-16f);
  *(float2*)(out + (size_t)n0 * 128 + lane * 2) =
      make_float2(aA.x * invA + bias[lane * 2],
                  aA.y * invA + bias[lane * 2 + 1]);
  if (has1)
    *(float2*)(out + (size_t)n1r * 128 + lane * 2) =
        make_float2(aB.x * invB + bias[lane * 2],
                    aB.y * invB + bias[lane * 2 + 1]);
}

// ------- global max pool over sorted batch (both encoders, 1 launch) ---
__global__ void pool_max2(const float* __restrict__ x, const int* __restrict__ bt1,
                          const int* __restrict__ bt2, float* __restrict__ emb) {
  __shared__ int lohi[2];
  const int enc = blockIdx.x >> 8;
  const int g = blockIdx.x & 255;
  const int* batch = enc ? bt2 : bt1;
  const float* xx = x + (size_t)enc * kN * 128;
  if (threadIdx.x == 0) {
    int lo = 0, hi = kN;
    while (lo < hi) {
      const int mid = (lo + hi) >> 1;
      if (batch[mid] < g) lo = mid + 1; else hi = mid;
    }
    lohi[0] = lo;
    hi = kN;
    while (lo < hi) {
      const int mid = (lo + hi) >> 1;
      if (batch[mid] < g + 1) lo = mid + 1; else hi = mid;
    }
    lohi[1] = lo;
  }
  __syncthreads();
  const int lo = lohi[0], hi = lohi[1];
  const int c = threadIdx.x;  // 128 channels
  float m = -1e30f;
  for (int nid = lo; nid < hi; ++nid) m = fmaxf(m, xx[(size_t)nid * 128 + c]);
  emb[(size_t)blockIdx.x * 128 + c] = (lo < hi) ? m : 0.f;
}
// ------- single-encoder pool (fallback path) --------------------------
__global__ void pool_max(const float* __restrict__ x, const int* __restrict__ batch,
                         float* __restrict__ emb, int n_nodes) {
  __shared__ int lohi[2];
  const int g = blockIdx.x;
  if (threadIdx.x == 0) {
    int lo = 0, hi = n_nodes;
    while (lo < hi) {
      const int mid = (lo + hi) >> 1;
      if (batch[mid] < g) lo = mid + 1; else hi = mid;
    }
    lohi[0] = lo;
    hi = n_nodes;
    while (lo < hi) {
      const int mid = (lo + hi) >> 1;
      if (batch[mid] < g + 1) lo = mid + 1; else hi = mid;
    }
    lohi[1] = lo;
  }
  __syncthreads();
  const int lo = lohi[0], hi = lohi[1];
  const int c = threadIdx.x;  // 128 channels
  float m = -1e30f;
  for (int nid = lo; nid < hi; ++nid) m = fmaxf(m, x[(size_t)nid * 128 + c]);
  emb[g * 128 + c] = (lo < hi) ? m : 0.f;
}

// ---------------- final MLP head --------------------------------------
__global__ void mlp_head(const float* __restrict__ e1, const float* __restrict__ e2,
                         const float* __restrict__ mw1, const float* __restrict__ mb1,
                         const float* __restrict__ mw2, const float* __restrict__ mb2,
                         float* __restrict__ out) {
  __shared__ float z[256];
  __shared__ float red[128];
  const int g = blockIdx.x;
  const int j = threadIdx.x;  // 128
  z[j] = e1[g * 128 + j];
  z[j + 128] = e2[g * 128 + j];
  __syncthreads();
  float acc = mb1[j];
  for (int k = 0; k < 256; ++k) acc = fmaf(z[k], mw1[k * 128 + j], acc);
  acc = fmaxf(acc, 0.f) * mw2[j];
  red[j] = acc;
  __syncthreads();
  for (int s = 64; s > 0; s >>= 1) {
    if (j < s) red[j] += red[j + s];
    __syncthreads();
  }
  if (j == 0) out[g] = red[0] + mb2[0];
}

// ---------------- launcher --------------------------------------------
namespace {
struct Bufs {
  _Float16 *R1h, *R2h;
  float *R1f, *R2f, *asrc, *adst;
  int *cnt, *start, *cursor, *csr, *total;
  _Float16 *Wth1, *Wth2, *Wth3;
  float* emb;
  size_t need;
};

Bufs plan(void* d_ws, int M, int E) {
  Bufs b;
  char* w = (char*)d_ws;
  size_t off = 0;
  auto take = [&](size_t bytes) -> void* {
    void* p = w + off;
    off += (bytes + 255) & ~(size_t)255;
    return p;
  };
  b.R1h = (_Float16*)take((size_t)M * 512 * 2);  // f16 activations
  b.R1f = (float*)b.R1h;                         // layer-3 out alias [M,128]
  b.R2h = (_Float16*)take((size_t)M * 512 * 2);  // h f16 (l3 h f16 [M,128])
  b.R2f = (float*)b.R2h;
  b.asrc = (float*)take((size_t)M * 4 * 4);      // (kept for ws layout stability)
  b.adst = (float*)take((size_t)M * 4 * 4);
  b.cnt = (int*)take((size_t)M * 4);
  b.start = (int*)take((size_t)M * 4);
  b.cursor = (int*)take((size_t)M * 4);
  b.csr = (int*)take((size_t)E * 4);
  b.total = (int*)take(256);
  b.Wth1 = (_Float16*)take((size_t)64 * 512 * 2);
  b.Wth2 = (_Float16*)take((size_t)512 * 512 * 2);
  b.Wth3 = (_Float16*)take((size_t)512 * 128 * 2);
  b.emb = (float*)take((size_t)2 * kG * 128 * 4);
  b.need = off;
  return b;
}

void run_layers(const Bufs& b, void* const* d_in, int M, hipStream_t stream) {
  const float* as1 = (const float*)d_in[7];
  const float* ad1 = (const float*)d_in[8];
  const float* b1 = (const float*)d_in[9];
  const float* as2 = (const float*)d_in[11];
  const float* ad2 = (const float*)d_in[12];
  const float* b2 = (const float*)d_in[13];
  const float* as3 = (const float*)d_in[15];
  const float* ad3 = (const float*)d_in[16];
  const float* b3 = (const float*)d_in[17];
  const int aggBlocks = (((M + 1) / 2) * 64 + 255) / 256;  // 2 nodes/wave
  const int RT128 = (M + 127) / 128;
  const int SP128 = (RT128 + 7) / 8;      // 128-row tile groups (XCD map)
  const int RT256 = (M + 255) / 256;
  const int SP256 = (RT256 + 7) / 8;      // 256-row tile groups

  // layer 1: [M,64] @ [64,512], BM=128, RING=3 (K=64: small tile — R9)
  gemm_ring<1, 128, 256, 2, 3><<<SP128 * 16, 256, 0, stream>>>(
      b.R1h, b.Wth1, b.R2h, M, 512, 64);
  gat_agg4<<<aggBlocks, 256, 0, stream>>>(b.R2h, as1, ad1, b.start, b.cnt,
                                          b.csr, b1, b.R1h, M);
  // layer 2: [M,512] @ [512,512], BM=256, RING=2 (64KB -> 2 blocks/CU)
  gemm_ring<1, 256, 256, 2, 2><<<SP256 * 16, 512, 0, stream>>>(
      b.R1h, b.Wth2, b.R2h, M, 512, 512);
  gat_agg4<<<aggBlocks, 256, 0, stream>>>(b.R2h, as2, ad2, b.start, b.cnt,
                                          b.csr, b2, b.R1h, M);
  // layer 3: [M,512] @ [512,128], BM=128, RING=3, h -> f16
  gemm_ring<1, 128, 128, 1, 3><<<SP128 * 8, 256, 0, stream>>>(
      b.R1h, b.Wth3, b.R2h, M, 128, 512);
  gat_agg_l3<<<aggBlocks, 256, 0, stream>>>(b.R2h, as3, ad3, b.start, b.cnt,
                                            b.csr, b3, b.R1f, M);
}
}  // namespace

extern "C" void kernel_launch(void* const* d_in, const int* in_sizes, int n_in,
                              void* d_out, int out_size, void* d_ws, size_t ws_size,
                              hipStream_t stream) {
  (void)in_sizes; (void)n_in; (void)out_size;
  const float* W1 = (const float*)d_in[6];
  const float* W2 = (const float*)d_in[10];
  const float* W3 = (const float*)d_in[14];
  const float* mw1 = (const float*)d_in[18];
  const float* mb1 = (const float*)d_in[19];
  const float* mw2 = (const float*)d_in[20];
  const float* mb2 = (const float*)d_in[21];

  // Prefer combined (both encoders batched, M=2N) if it fits the workspace.
  Bufs bc = plan(d_ws, 2 * kN, 2 * kE2);
  const bool combined = bc.need <= ws_size;
  Bufs b = combined ? bc : plan(d_ws, kN, kE2);

  const int wtot = 64 * 512 + 512 * 512 + 512 * 128;
  if (combined) {
    const int M = 2 * kN;
    const int* ei0 = (const int*)d_in[1];
    const int* ei1 = (const int*)d_in[4];
    prep_all<<<(M * 64 + wtot + 255) / 256, 256, 0, stream>>>(
        (const float*)d_in[0], (const float*)d_in[3], b.R1h, b.cnt, b.total,
        W1, b.Wth1, W2, b.Wth2, W3, b.Wth3);
    count_edges2<<<(2 * kE + 255) / 256, 256, 0, stream>>>(ei0 + kE, ei1 + kE,
                                                           b.cnt);
    alloc_ranges<<<(M + 255) / 256, 256, 0, stream>>>(b.cnt, b.start, b.cursor,
                                                      b.total, b.csr, M);
    fill_edges2<<<(2 * kE + 255) / 256, 256, 0, stream>>>(ei0, ei0 + kE, ei1,
                                                          ei1 + kE, b.cursor, b.csr);
    run_layers(b, d_in, M, stream);
    pool_max2<<<2 * kG, 128, 0, stream>>>(b.R1f, (const int*)d_in[2],
                                          (const int*)d_in[5], b.emb);
  } else {
    wt_split_all<<<(wtot + 255) / 256, 256, 0, stream>>>(W1, b.Wth1, W2, b.Wth2,
                                                         W3, b.Wth3);
    for (int enc = 0; enc < 2; ++enc) {
      const float* x = (const float*)d_in[enc * 3 + 0];
      const int* ei = (const int*)d_in[enc * 3 + 1];
      const int* batch = (const int*)d_in[enc * 3 + 2];
      prep<<<(kN * 64 + 255) / 256, 256, 0, stream>>>(x, b.R1h, b.cnt, b.total,
                                                      kN * 64, kN);
      count_edges<<<(kE + 255) / 256, 256, 0, stream>>>(ei + kE, b.cnt, kE);
      alloc_ranges<<<(kN + 255) / 256, 256, 0, stream>>>(b.cnt, b.start, b.cursor,
                                                         b.total, b.csr, kN);
      fill_edges<<<(kE + 255) / 256, 256, 0, stream>>>(ei, ei + kE, b.cursor, b.csr,
                                                       kE);
      run_layers(b, d_in, kN, stream);
      pool_max<<<kG, 128, 0, stream>>>(b.R1f, batch, b.emb + (size_t)enc * kG * 128,
                                       kN);
    }
  }
  mlp_head<<<kG, 128, 0, stream>>>(b.emb, b.emb + (size_t)kG * 128, mw1, mb1, mw2,
                                   mb2, (float*)d_out);
}